// Round 1
// baseline (3642.928 us; speedup 1.0000x reference)
//
#include <hip/hip_runtime.h>
#include <hip/hip_bf16.h>
#include <cstddef>

// Shapes (fixed):
// x_seq: (T=16, B=32, 1, 100, 368) binary {0,1} fp32
// conv1: w1 (16,1,5,5) s2 p2   -> (32,16,50,184)
// conv2: w2 (32,16,3,3) s2 p1  -> (32,32,25,92)
// convd: wd (64,32,3,3) s1 p1  -> (32,64,25,92), relu
// convT1: wt1 (64,32,4,4) s2 p1 -> (32,32,50,184), relu
// convT2: wt2 (32,2,4,4) s2 p1  -> (32,2,100,368), softplus
// out: two (32,1,100,368) tensors concatenated flat.

#define T_STEPS 16
#define NB 32
#define H0 100
#define W0 368
#define C1 16
#define H1 50
#define W1 184
#define C2 32
#define H2 25
#define W2 92
#define CD 64

// ---------------- Kernel A: conv1 + LIF over all 16 timesteps ----------------
// One thread per (b, y1, x1). m1[16] in registers. Emits packed spike bitmask.
__global__ void k_snn1(const float* __restrict__ x, const float* __restrict__ w1,
                       unsigned short* __restrict__ s1m) {
    __shared__ float sw[C1 * 25];
    for (int i = threadIdx.x; i < C1 * 25; i += blockDim.x) sw[i] = w1[i];
    __syncthreads();

    int idx = blockIdx.x * blockDim.x + threadIdx.x;
    const int NPOS = NB * H1 * W1; // 294400
    if (idx >= NPOS) return;
    int x1 = idx % W1;
    int tmp = idx / W1;
    int y1 = tmp % H1;
    int b  = tmp / H1;

    float m1[C1];
#pragma unroll
    for (int c = 0; c < C1; ++c) m1[c] = 0.f;

    const int iy0 = 2 * y1 - 2;
    const int ix0 = 2 * x1 - 2;

    for (int t = 0; t < T_STEPS; ++t) {
        const float* xp = x + ((size_t)t * NB + b) * (H0 * W0);
#pragma unroll
        for (int c = 0; c < C1; ++c) m1[c] *= 0.5f;
#pragma unroll
        for (int ky = 0; ky < 5; ++ky) {
            int iy = iy0 + ky;
            if (iy < 0 || iy >= H0) continue;
#pragma unroll
            for (int kx = 0; kx < 5; ++kx) {
                int ix = ix0 + kx;
                if (ix < 0 || ix >= W0) continue;
                float v = xp[iy * W0 + ix];
                if (v != 0.f) { // binary input: add weights
                    int k = ky * 5 + kx;
#pragma unroll
                    for (int c = 0; c < C1; ++c) m1[c] += sw[c * 25 + k];
                }
            }
        }
        unsigned int mask = 0;
#pragma unroll
        for (int c = 0; c < C1; ++c) {
            if (m1[c] >= 1.0f) { mask |= (1u << c); m1[c] = 0.f; }
        }
        s1m[(size_t)t * NPOS + idx] = (unsigned short)mask;
    }
}

// ---------------- Kernel B: conv2 + LIF over all 16 timesteps ----------------
// One thread per (b, y2, x2). m2[32] in registers. Input: packed s1 bitmasks.
// Writes final mem2 as NCHW.
__global__ void k_snn2(const unsigned short* __restrict__ s1m,
                       const float* __restrict__ w2, float* __restrict__ mem2) {
    // LDS weights re-laid-out as [pos(9)][ci(16)][c2(32)]
    __shared__ float sw[9 * C1 * C2];
    for (int i = threadIdx.x; i < 9 * C1 * C2; i += blockDim.x) {
        int c2 = i & 31;
        int r = i >> 5;
        int ci = r & 15;
        int pos = r >> 4;
        sw[i] = w2[(c2 * C1 + ci) * 9 + pos];
    }
    __syncthreads();

    int idx = blockIdx.x * blockDim.x + threadIdx.x;
    const int NPOS = NB * H2 * W2; // 73600
    if (idx >= NPOS) return;
    int x2 = idx % W2;
    int tmp = idx / W2;
    int y2 = tmp % H2;
    int b  = tmp / H2;

    float m2[C2];
#pragma unroll
    for (int c = 0; c < C2; ++c) m2[c] = 0.f;

    const int S1POS = NB * H1 * W1;
    for (int t = 0; t < T_STEPS; ++t) {
#pragma unroll
        for (int c = 0; c < C2; ++c) m2[c] *= 0.5f;
        const unsigned short* spk = s1m + (size_t)t * S1POS + (size_t)b * (H1 * W1);
#pragma unroll
        for (int ky = 0; ky < 3; ++ky) {
            int iy = 2 * y2 + ky - 1;
            if (iy < 0 || iy >= H1) continue;
#pragma unroll
            for (int kx = 0; kx < 3; ++kx) {
                int ix = 2 * x2 + kx - 1;
                if (ix < 0 || ix >= W1) continue;
                unsigned int mask = spk[iy * W1 + ix];
                while (mask) {
                    int ci = __ffs(mask) - 1;
                    mask &= mask - 1;
                    const float* wrow = &sw[((ky * 3 + kx) * C1 + ci) * C2];
#pragma unroll
                    for (int c = 0; c < C2; ++c) m2[c] += wrow[c];
                }
            }
        }
#pragma unroll
        for (int c = 0; c < C2; ++c) {
            if (m2[c] >= 1.0f) m2[c] = 0.f;
        }
    }
#pragma unroll
    for (int c = 0; c < C2; ++c)
        mem2[(((size_t)b * C2 + c) * H2 + y2) * W2 + x2] = m2[c];
}

// ---------------- Kernel C: 3x3 conv (stride1 pad1) + bias + relu ----------------
// grid: (spatial/256, co=64, b=32)
__global__ void k_convd(const float* __restrict__ mem2, const float* __restrict__ wd,
                        const float* __restrict__ bd, float* __restrict__ h1) {
    int sp = blockIdx.x * blockDim.x + threadIdx.x; // 25*92 = 2300
    int co = blockIdx.y;
    int b  = blockIdx.z;
    if (sp >= H2 * W2) return;
    int xx = sp % W2, yy = sp / W2;
    float acc = bd[co];
    const float* wp = wd + (size_t)co * C2 * 9;
    const float* ip = mem2 + (size_t)b * C2 * (H2 * W2);
#pragma unroll
    for (int ky = 0; ky < 3; ++ky) {
        int iy = yy + ky - 1;
        if (iy < 0 || iy >= H2) continue;
#pragma unroll
        for (int kx = 0; kx < 3; ++kx) {
            int ix = xx + kx - 1;
            if (ix < 0 || ix >= W2) continue;
            const float* ipp = ip + iy * W2 + ix;
            const float* wpp = wp + ky * 3 + kx;
            for (int ci = 0; ci < C2; ++ci)
                acc += ipp[ci * (H2 * W2)] * wpp[ci * 9];
        }
    }
    h1[((size_t)b * CD + co) * (H2 * W2) + sp] = fmaxf(acc, 0.f);
}

// ---------------- Kernel D: convT 4x4 s2 p1 (64->32) + bias + relu ----------------
// grid: (spatial/256, co=32, b=32)
__global__ void k_convt1(const float* __restrict__ h1, const float* __restrict__ wt1,
                         const float* __restrict__ bt1, float* __restrict__ h2) {
    int sp = blockIdx.x * blockDim.x + threadIdx.x; // 50*184 = 9200
    int co = blockIdx.y;
    int b  = blockIdx.z;
    if (sp >= H1 * W1) return;
    int ox = sp % W1, oy = sp / W1;
    float acc = bt1[co];
    int iy_lo = ((oy + 1) >> 1) - 1;
    int ix_lo = ((ox + 1) >> 1) - 1;
#pragma unroll
    for (int dy = 0; dy < 2; ++dy) {
        int iy = iy_lo + dy;
        int ky = oy + 1 - 2 * iy;
        if (iy < 0 || iy >= H2 || ky < 0 || ky > 3) continue;
#pragma unroll
        for (int dx = 0; dx < 2; ++dx) {
            int ix = ix_lo + dx;
            int kx = ox + 1 - 2 * ix;
            if (ix < 0 || ix >= W2 || kx < 0 || kx > 3) continue;
            const float* ip = h1 + (size_t)b * CD * (H2 * W2) + iy * W2 + ix;
            const float* wp = wt1 + (co * 4 + ky) * 4 + kx; // wt1[ci][co][ky][kx]
            for (int ci = 0; ci < CD; ++ci)
                acc += ip[ci * (H2 * W2)] * wp[ci * (C2 * 16)];
        }
    }
    h2[((size_t)b * C2 + co) * (H1 * W1) + sp] = fmaxf(acc, 0.f);
}

// ---------------- Kernel E: convT 4x4 s2 p1 (32->2) + bias + softplus ----------------
// grid: (spatial/256, c=2, b=32). Writes split outputs.
__global__ void k_convt2(const float* __restrict__ h2, const float* __restrict__ wt2,
                         const float* __restrict__ bt2, float* __restrict__ out) {
    int sp = blockIdx.x * blockDim.x + threadIdx.x; // 100*368 = 36800
    int c = blockIdx.y;
    int b = blockIdx.z;
    if (sp >= H0 * W0) return;
    int ox = sp % W0, oy = sp / W0;
    float acc = bt2[c];
    int iy_lo = ((oy + 1) >> 1) - 1;
    int ix_lo = ((ox + 1) >> 1) - 1;
#pragma unroll
    for (int dy = 0; dy < 2; ++dy) {
        int iy = iy_lo + dy;
        int ky = oy + 1 - 2 * iy;
        if (iy < 0 || iy >= H1 || ky < 0 || ky > 3) continue;
#pragma unroll
        for (int dx = 0; dx < 2; ++dx) {
            int ix = ix_lo + dx;
            int kx = ox + 1 - 2 * ix;
            if (ix < 0 || ix >= W1 || kx < 0 || kx > 3) continue;
            const float* ip = h2 + (size_t)b * C2 * (H1 * W1) + iy * W1 + ix;
            const float* wp = wt2 + (c * 4 + ky) * 4 + kx; // wt2[ci][c][ky][kx]
            for (int ci = 0; ci < C2; ++ci)
                acc += ip[ci * (H1 * W1)] * wp[ci * (2 * 16)];
        }
    }
    // numerically stable softplus
    float v = fmaxf(acc, 0.f) + log1pf(expf(-fabsf(acc)));
    out[(size_t)c * (NB * H0 * W0) + (size_t)b * (H0 * W0) + sp] = v;
}

extern "C" void kernel_launch(void* const* d_in, const int* in_sizes, int n_in,
                              void* d_out, int out_size, void* d_ws, size_t ws_size,
                              hipStream_t stream) {
    const float* x   = (const float*)d_in[0];
    const float* w1  = (const float*)d_in[1];
    const float* w2  = (const float*)d_in[2];
    const float* wd  = (const float*)d_in[3];
    const float* bd  = (const float*)d_in[4];
    const float* wt1 = (const float*)d_in[5];
    const float* bt1 = (const float*)d_in[6];
    const float* wt2 = (const float*)d_in[7];
    const float* bt2 = (const float*)d_in[8];
    float* out = (float*)d_out;

    char* ws = (char*)d_ws;
    // workspace layout (bytes):
    // s1 masks: 16*32*50*184 * 2      =  9,420,800
    // mem2:     32*32*25*92  * 4      =  9,420,800
    // h1:       32*64*25*92  * 4      = 18,841,600
    // h2:       32*32*50*184 * 4      = 37,683,200
    // total ~75.4 MB
    unsigned short* s1m = (unsigned short*)ws;
    float* mem2 = (float*)(ws + 9420800);
    float* h1   = (float*)(ws + 18841600);
    float* h2   = (float*)(ws + 37683200);

    {
        int n = NB * H1 * W1; // 294400
        k_snn1<<<(n + 255) / 256, 256, 0, stream>>>(x, w1, s1m);
    }
    {
        int n = NB * H2 * W2; // 73600
        k_snn2<<<(n + 255) / 256, 256, 0, stream>>>(s1m, w2, mem2);
    }
    {
        dim3 g((H2 * W2 + 255) / 256, CD, NB);
        k_convd<<<g, 256, 0, stream>>>(mem2, wd, bd, h1);
    }
    {
        dim3 g((H1 * W1 + 255) / 256, C2, NB);
        k_convt1<<<g, 256, 0, stream>>>(h1, wt1, bt1, h2);
    }
    {
        dim3 g((H0 * W0 + 255) / 256, 2, NB);
        k_convt2<<<g, 256, 0, stream>>>(h2, wt2, bt2, out);
    }
}

// Round 2
// 973.818 us; speedup vs baseline: 3.7409x; 3.7409x over previous
//
#include <hip/hip_runtime.h>
#include <hip/hip_bf16.h>
#include <cstddef>

// Shapes (fixed):
// x_seq: (T=16, B=32, 1, 100, 368) binary {0,1} fp32
// conv1: w1 (16,1,5,5) s2 p2   -> (32,16,50,184)
// conv2: w2 (32,16,3,3) s2 p1  -> (32,32,25,92)
// convd: wd (64,32,3,3) s1 p1  -> (32,64,25,92), relu
// convT1: wt1 (64,32,4,4) s2 p1 -> (32,32,50,184), relu
// convT2: wt2 (32,2,4,4) s2 p1  -> (32,2,100,368), softplus

#define T_STEPS 16
#define NB 32
#define H0 100
#define W0 368
#define C1 16
#define H1 50
#define W1 184
#define C2 32
#define H2 25
#define W2 92
#define CD 64
#define WPR 6  // packed uint64 words per input row (368 bits -> 6 words)

// ---------------- Kernel P: bit-pack binary input ----------------
// One wave per packed word: 64 lanes read 64 consecutive floats, ballot.
__global__ void k_pack(const float* __restrict__ x, unsigned long long* __restrict__ xb) {
    long long gid = (long long)blockIdx.x * blockDim.x + threadIdx.x;
    long long widx = gid >> 6;
    int lane = (int)(gid & 63);
    const long long NWORDS = (long long)T_STEPS * NB * H0 * WPR;
    if (widx >= NWORDS) return;
    int wcol = (int)(widx % WPR);
    long long rowid = widx / WPR;          // over T*B*H0
    int y = (int)(rowid % H0);
    long long tb = rowid / H0;             // t*NB + b
    int col = wcol * 64 + lane;
    float v = 0.f;
    if (col < W0) v = x[(tb * H0 + y) * W0 + col];
    unsigned long long mask = __ballot(v != 0.f);
    if (lane == 0) xb[widx] = mask;
}

// ---------------- Kernel A: conv1 + LIF over all 16 timesteps ----------------
// One thread per (b, y1, x1). m1[16] in registers. Reads packed input bits.
__global__ void k_snn1(const unsigned long long* __restrict__ xb,
                       const float* __restrict__ w1,
                       unsigned short* __restrict__ s1m) {
    __shared__ float sw[25 * C1]; // [k][c]
    for (int i = threadIdx.x; i < 25 * C1; i += blockDim.x) {
        int k = i >> 4, c = i & 15;
        sw[i] = w1[c * 25 + k];
    }
    __syncthreads();

    int idx = blockIdx.x * blockDim.x + threadIdx.x;
    const int NPOS = NB * H1 * W1; // 294400
    if (idx >= NPOS) return;
    int x1 = idx % W1;
    int tmp = idx / W1;
    int y1 = tmp % H1;
    int b  = tmp / H1;

    float m1[C1];
#pragma unroll
    for (int c = 0; c < C1; ++c) m1[c] = 0.f;

    const int iy0 = 2 * y1 - 2;
    const int ix0 = 2 * x1 - 2;
    const int wi = ix0 >> 6;        // arithmetic shift: -2 -> -1
    const int s  = ix0 & 63;

    for (int t = 0; t < T_STEPS; ++t) {
#pragma unroll
        for (int c = 0; c < C1; ++c) m1[c] *= 0.5f;

        const unsigned long long* xp = xb + ((size_t)(t * NB + b) * H0) * WPR;
        unsigned int bits25 = 0;
#pragma unroll
        for (int ky = 0; ky < 5; ++ky) {
            int iy = iy0 + ky;
            if (iy < 0 || iy >= H0) continue;
            const unsigned long long* row = xp + (size_t)iy * WPR;
            unsigned long long a = (wi >= 0) ? row[wi] : 0ull;
            unsigned long long bw = (wi + 1 < WPR) ? row[wi + 1] : 0ull;
            unsigned long long chunk = a >> s;
            if (s) chunk |= (bw << (64 - s));
            bits25 |= ((unsigned int)chunk & 31u) << (5 * ky);
        }
        // walk set bits in ascending k = ky*5+kx (same add order as dense ref loop)
        while (bits25) {
            int k = __ffs(bits25) - 1;
            bits25 &= bits25 - 1;
            const float* wk = &sw[k * C1];
#pragma unroll
            for (int c = 0; c < C1; ++c) m1[c] += wk[c];
        }
        unsigned int mask = 0;
#pragma unroll
        for (int c = 0; c < C1; ++c) {
            if (m1[c] >= 1.0f) { mask |= (1u << c); m1[c] = 0.f; }
        }
        s1m[(size_t)t * NPOS + idx] = (unsigned short)mask;
    }
}

// ---------------- Kernel B: conv2 + LIF over all 16 timesteps ----------------
__global__ void k_snn2(const unsigned short* __restrict__ s1m,
                       const float* __restrict__ w2, float* __restrict__ mem2) {
    // LDS weights re-laid-out as [pos(9)][ci(16)][c2(32)]
    __shared__ float sw[9 * C1 * C2];
    for (int i = threadIdx.x; i < 9 * C1 * C2; i += blockDim.x) {
        int c2 = i & 31;
        int r = i >> 5;
        int ci = r & 15;
        int pos = r >> 4;
        sw[i] = w2[(c2 * C1 + ci) * 9 + pos];
    }
    __syncthreads();

    int idx = blockIdx.x * blockDim.x + threadIdx.x;
    const int NPOS = NB * H2 * W2; // 73600
    if (idx >= NPOS) return;
    int x2 = idx % W2;
    int tmp = idx / W2;
    int y2 = tmp % H2;
    int b  = tmp / H2;

    float m2[C2];
#pragma unroll
    for (int c = 0; c < C2; ++c) m2[c] = 0.f;

    const int S1POS = NB * H1 * W1;
    for (int t = 0; t < T_STEPS; ++t) {
#pragma unroll
        for (int c = 0; c < C2; ++c) m2[c] *= 0.5f;
        const unsigned short* spk = s1m + (size_t)t * S1POS + (size_t)b * (H1 * W1);
#pragma unroll
        for (int ky = 0; ky < 3; ++ky) {
            int iy = 2 * y2 + ky - 1;
            if (iy < 0 || iy >= H1) continue;
#pragma unroll
            for (int kx = 0; kx < 3; ++kx) {
                int ix = 2 * x2 + kx - 1;
                if (ix < 0 || ix >= W1) continue;
                unsigned int mask = spk[iy * W1 + ix];
                while (mask) {
                    int ci = __ffs(mask) - 1;
                    mask &= mask - 1;
                    const float* wrow = &sw[((ky * 3 + kx) * C1 + ci) * C2];
#pragma unroll
                    for (int c = 0; c < C2; ++c) m2[c] += wrow[c];
                }
            }
        }
#pragma unroll
        for (int c = 0; c < C2; ++c) {
            if (m2[c] >= 1.0f) m2[c] = 0.f;
        }
    }
#pragma unroll
    for (int c = 0; c < C2; ++c)
        mem2[(((size_t)b * C2 + c) * H2 + y2) * W2 + x2] = m2[c];
}

// ---------------- Kernel C: 3x3 conv (stride1 pad1) + bias + relu ----------------
__global__ void k_convd(const float* __restrict__ mem2, const float* __restrict__ wd,
                        const float* __restrict__ bd, float* __restrict__ h1) {
    int sp = blockIdx.x * blockDim.x + threadIdx.x; // 25*92 = 2300
    int co = blockIdx.y;
    int b  = blockIdx.z;
    if (sp >= H2 * W2) return;
    int xx = sp % W2, yy = sp / W2;
    float acc = bd[co];
    const float* wp = wd + (size_t)co * C2 * 9;
    const float* ip = mem2 + (size_t)b * C2 * (H2 * W2);
#pragma unroll
    for (int ky = 0; ky < 3; ++ky) {
        int iy = yy + ky - 1;
        if (iy < 0 || iy >= H2) continue;
#pragma unroll
        for (int kx = 0; kx < 3; ++kx) {
            int ix = xx + kx - 1;
            if (ix < 0 || ix >= W2) continue;
            const float* ipp = ip + iy * W2 + ix;
            const float* wpp = wp + ky * 3 + kx;
            for (int ci = 0; ci < C2; ++ci)
                acc += ipp[ci * (H2 * W2)] * wpp[ci * 9];
        }
    }
    h1[((size_t)b * CD + co) * (H2 * W2) + sp] = fmaxf(acc, 0.f);
}

// ---------------- Kernel D: convT 4x4 s2 p1 (64->32) + bias + relu ----------------
__global__ void k_convt1(const float* __restrict__ h1, const float* __restrict__ wt1,
                         const float* __restrict__ bt1, float* __restrict__ h2) {
    int sp = blockIdx.x * blockDim.x + threadIdx.x; // 50*184 = 9200
    int co = blockIdx.y;
    int b  = blockIdx.z;
    if (sp >= H1 * W1) return;
    int ox = sp % W1, oy = sp / W1;
    float acc = bt1[co];
    int iy_lo = ((oy + 1) >> 1) - 1;
    int ix_lo = ((ox + 1) >> 1) - 1;
#pragma unroll
    for (int dy = 0; dy < 2; ++dy) {
        int iy = iy_lo + dy;
        int ky = oy + 1 - 2 * iy;
        if (iy < 0 || iy >= H2 || ky < 0 || ky > 3) continue;
#pragma unroll
        for (int dx = 0; dx < 2; ++dx) {
            int ix = ix_lo + dx;
            int kx = ox + 1 - 2 * ix;
            if (ix < 0 || ix >= W2 || kx < 0 || kx > 3) continue;
            const float* ip = h1 + (size_t)b * CD * (H2 * W2) + iy * W2 + ix;
            const float* wp = wt1 + (co * 4 + ky) * 4 + kx; // wt1[ci][co][ky][kx]
            for (int ci = 0; ci < CD; ++ci)
                acc += ip[ci * (H2 * W2)] * wp[ci * (C2 * 16)];
        }
    }
    h2[((size_t)b * C2 + co) * (H1 * W1) + sp] = fmaxf(acc, 0.f);
}

// ---------------- Kernel E: convT 4x4 s2 p1 (32->2) + bias + softplus ----------------
__global__ void k_convt2(const float* __restrict__ h2, const float* __restrict__ wt2,
                         const float* __restrict__ bt2, float* __restrict__ out) {
    int sp = blockIdx.x * blockDim.x + threadIdx.x; // 100*368 = 36800
    int c = blockIdx.y;
    int b = blockIdx.z;
    if (sp >= H0 * W0) return;
    int ox = sp % W0, oy = sp / W0;
    float acc = bt2[c];
    int iy_lo = ((oy + 1) >> 1) - 1;
    int ix_lo = ((ox + 1) >> 1) - 1;
#pragma unroll
    for (int dy = 0; dy < 2; ++dy) {
        int iy = iy_lo + dy;
        int ky = oy + 1 - 2 * iy;
        if (iy < 0 || iy >= H1 || ky < 0 || ky > 3) continue;
#pragma unroll
        for (int dx = 0; dx < 2; ++dx) {
            int ix = ix_lo + dx;
            int kx = ox + 1 - 2 * ix;
            if (ix < 0 || ix >= W1 || kx < 0 || kx > 3) continue;
            const float* ip = h2 + (size_t)b * C2 * (H1 * W1) + iy * W1 + ix;
            const float* wp = wt2 + (c * 4 + ky) * 4 + kx; // wt2[ci][c][ky][kx]
            for (int ci = 0; ci < C2; ++ci)
                acc += ip[ci * (H1 * W1)] * wp[ci * (2 * 16)];
        }
    }
    float v = fmaxf(acc, 0.f) + log1pf(expf(-fabsf(acc)));
    out[(size_t)c * (NB * H0 * W0) + (size_t)b * (H0 * W0) + sp] = v;
}

extern "C" void kernel_launch(void* const* d_in, const int* in_sizes, int n_in,
                              void* d_out, int out_size, void* d_ws, size_t ws_size,
                              hipStream_t stream) {
    const float* x   = (const float*)d_in[0];
    const float* w1  = (const float*)d_in[1];
    const float* w2  = (const float*)d_in[2];
    const float* wd  = (const float*)d_in[3];
    const float* bd  = (const float*)d_in[4];
    const float* wt1 = (const float*)d_in[5];
    const float* bt1 = (const float*)d_in[6];
    const float* wt2 = (const float*)d_in[7];
    const float* bt2 = (const float*)d_in[8];
    float* out = (float*)d_out;

    char* ws = (char*)d_ws;
    // workspace layout (bytes), total 75,366,400:
    //   s1m : [0,          9,420,800)   uint16 spikes, live snn1->snn2
    //   mem2: [9,420,800, 18,841,600)   live snn2->convd
    //   h1  : [18,841,600, 37,683,200)  live convd->convt1
    //   h2  : [37,683,200, 75,366,400)  live convt1->convt2
    //   xb  : overlays h2's slot (2,457,600 B) — dead before h2 is written
    unsigned short* s1m = (unsigned short*)ws;
    float* mem2 = (float*)(ws + 9420800);
    float* h1   = (float*)(ws + 18841600);
    float* h2   = (float*)(ws + 37683200);
    unsigned long long* xb = (unsigned long long*)(ws + 37683200);

    {
        long long nthreads = (long long)T_STEPS * NB * H0 * WPR * 64; // 19.66M
        int blocks = (int)((nthreads + 255) / 256);
        k_pack<<<blocks, 256, 0, stream>>>(x, xb);
    }
    {
        int n = NB * H1 * W1; // 294400
        k_snn1<<<(n + 255) / 256, 256, 0, stream>>>(xb, w1, s1m);
    }
    {
        int n = NB * H2 * W2; // 73600
        k_snn2<<<(n + 255) / 256, 256, 0, stream>>>(s1m, w2, mem2);
    }
    {
        dim3 g((H2 * W2 + 255) / 256, CD, NB);
        k_convd<<<g, 256, 0, stream>>>(mem2, wd, bd, h1);
    }
    {
        dim3 g((H1 * W1 + 255) / 256, C2, NB);
        k_convt1<<<g, 256, 0, stream>>>(h1, wt1, bt1, h2);
    }
    {
        dim3 g((H0 * W0 + 255) / 256, 2, NB);
        k_convt2<<<g, 256, 0, stream>>>(h2, wt2, bt2, out);
    }
}

// Round 3
// 381.102 us; speedup vs baseline: 9.5589x; 2.5553x over previous
//
#include <hip/hip_runtime.h>
#include <hip/hip_bf16.h>
#include <cstddef>

// Shapes (fixed):
// x_seq: (T=16, B=32, 1, 100, 368) binary {0,1} fp32
// conv1: w1 (16,1,5,5) s2 p2   -> (32,16,50,184)
// conv2: w2 (32,16,3,3) s2 p1  -> (32,32,25,92)
// convd: wd (64,32,3,3) s1 p1  -> (32,64,25,92), relu
// convT1: wt1 (64,32,4,4) s2 p1 -> (32,32,50,184), relu
// convT2: wt2 (32,2,4,4) s2 p1  -> (32,2,100,368), softplus

#define T_STEPS 16
#define NB 32
#define H0 100
#define W0 368
#define C1 16
#define H1 50
#define W1 184
#define C2 32
#define H2 25
#define W2 92
#define CD 64
#define WPR 6  // packed uint64 words per input row (368 bits -> 6 words)

// ---------------- Kernel P: bit-pack binary input ----------------
__global__ __launch_bounds__(256) void k_pack(const float* __restrict__ x,
                                              unsigned long long* __restrict__ xb) {
    long long gid = (long long)blockIdx.x * blockDim.x + threadIdx.x;
    long long widx = gid >> 6;
    int lane = (int)(gid & 63);
    const long long NWORDS = (long long)T_STEPS * NB * H0 * WPR;
    if (widx >= NWORDS) return;
    int wcol = (int)(widx % WPR);
    long long rowid = widx / WPR;
    int y = (int)(rowid % H0);
    long long tb = rowid / H0;
    int col = wcol * 64 + lane;
    float v = 0.f;
    if (col < W0) v = x[(tb * H0 + y) * W0 + col];
    unsigned long long mask = __ballot(v != 0.f);
    if (lane == 0) xb[widx] = mask;
}

// ---------------- Kernel A: conv1 + LIF over all 16 timesteps ----------------
__global__ __launch_bounds__(256) void k_snn1(const unsigned long long* __restrict__ xb,
                                              const float* __restrict__ w1,
                                              unsigned short* __restrict__ s1m) {
    __shared__ float sw[25 * C1]; // [k][c]
    for (int i = threadIdx.x; i < 25 * C1; i += blockDim.x) {
        int k = i >> 4, c = i & 15;
        sw[i] = w1[c * 25 + k];
    }
    __syncthreads();

    int idx = blockIdx.x * blockDim.x + threadIdx.x;
    const int NPOS = NB * H1 * W1; // 294400
    if (idx >= NPOS) return;
    int x1 = idx % W1;
    int tmp = idx / W1;
    int y1 = tmp % H1;
    int b  = tmp / H1;

    float m1[C1];
#pragma unroll
    for (int c = 0; c < C1; ++c) m1[c] = 0.f;

    const int iy0 = 2 * y1 - 2;
    const int ix0 = 2 * x1 - 2;
    const int wi = ix0 >> 6;
    const int s  = ix0 & 63;

    for (int t = 0; t < T_STEPS; ++t) {
#pragma unroll
        for (int c = 0; c < C1; ++c) m1[c] *= 0.5f;

        const unsigned long long* xp = xb + ((size_t)(t * NB + b) * H0) * WPR;
        unsigned int bits25 = 0;
#pragma unroll
        for (int ky = 0; ky < 5; ++ky) {
            int iy = iy0 + ky;
            if (iy < 0 || iy >= H0) continue;
            const unsigned long long* row = xp + (size_t)iy * WPR;
            unsigned long long a = (wi >= 0) ? row[wi] : 0ull;
            unsigned long long bw = (wi + 1 < WPR) ? row[wi + 1] : 0ull;
            unsigned long long chunk = a >> s;
            if (s) chunk |= (bw << (64 - s));
            bits25 |= ((unsigned int)chunk & 31u) << (5 * ky);
        }
        while (bits25) {
            int k = __ffs(bits25) - 1;
            bits25 &= bits25 - 1;
            const float* wk = &sw[k * C1];
#pragma unroll
            for (int c = 0; c < C1; ++c) m1[c] += wk[c];
        }
        unsigned int mask = 0;
#pragma unroll
        for (int c = 0; c < C1; ++c) {
            if (m1[c] >= 1.0f) { mask |= (1u << c); m1[c] = 0.f; }
        }
        s1m[(size_t)t * NPOS + idx] = (unsigned short)mask;
    }
}

// ---------------- Kernel B: conv2 + LIF over all 16 timesteps ----------------
__global__ __launch_bounds__(256) void k_snn2(const unsigned short* __restrict__ s1m,
                                              const float* __restrict__ w2,
                                              float* __restrict__ mem2) {
    // LDS weights as [pos(9)][ci(16)] rows of stride 36 (9*row mod 32 distinct -> conflict-free b128)
    __shared__ float sw[9 * C1 * 36];
    for (int i = threadIdx.x; i < 9 * C1 * C2; i += blockDim.x) {
        int c2 = i & 31;
        int r = i >> 5;          // pos*16 + ci
        int ci = r & 15;
        int pos = r >> 4;
        sw[r * 36 + c2] = w2[(c2 * C1 + ci) * 9 + pos];
    }
    __syncthreads();

    int idx = blockIdx.x * blockDim.x + threadIdx.x;
    const int NPOS = NB * H2 * W2; // 73600
    if (idx >= NPOS) return;
    int x2 = idx % W2;
    int tmp = idx / W2;
    int y2 = tmp % H2;
    int b  = tmp / H2;

    float m2[C2];
#pragma unroll
    for (int c = 0; c < C2; ++c) m2[c] = 0.f;

    const int S1POS = NB * H1 * W1;
    for (int t = 0; t < T_STEPS; ++t) {
#pragma unroll
        for (int c = 0; c < C2; ++c) m2[c] *= 0.5f;
        const unsigned short* spk = s1m + (size_t)t * S1POS + (size_t)b * (H1 * W1);
#pragma unroll
        for (int ky = 0; ky < 3; ++ky) {
            int iy = 2 * y2 + ky - 1;
            if (iy < 0 || iy >= H1) continue;
#pragma unroll
            for (int kx = 0; kx < 3; ++kx) {
                int ix = 2 * x2 + kx - 1;
                if (ix < 0 || ix >= W1) continue;
                unsigned int mask = spk[iy * W1 + ix];
                while (mask) {
                    int ci = __ffs(mask) - 1;
                    mask &= mask - 1;
                    const float* wrow = &sw[((ky * 3 + kx) * C1 + ci) * 36];
#pragma unroll
                    for (int c = 0; c < C2; ++c) m2[c] += wrow[c];
                }
            }
        }
#pragma unroll
        for (int c = 0; c < C2; ++c) {
            if (m2[c] >= 1.0f) m2[c] = 0.f;
        }
    }
#pragma unroll
    for (int c = 0; c < C2; ++c)
        mem2[(((size_t)b * C2 + c) * H2 + y2) * W2 + x2] = m2[c];
}

// ---------------- Kernel R: repack decoder weights for uniform s_load ----------------
// wt1k[((par*64+ci)*4 + tap)*32 + co], wdk[(ci*9+pos)*64 + co], wt2k[((par*32+ci)*4+tap)*2+co]
__global__ __launch_bounds__(256) void k_repack(const float* __restrict__ wt1,
                                                const float* __restrict__ wd,
                                                const float* __restrict__ wt2,
                                                float* __restrict__ wt1k,
                                                float* __restrict__ wdk,
                                                float* __restrict__ wt2k) {
    int gid = blockIdx.x * blockDim.x + threadIdx.x;
    if (gid < 32768) {
        int idx = gid;
        int co = idx & 31, tap = (idx >> 5) & 3, ci = (idx >> 7) & 63, par = idx >> 13;
        int dyt = tap >> 1, dxt = tap & 1;
        int ry = par >> 1, rx = par & 1;
        int ky = ry ? (dyt ? 0 : 2) : (dyt ? 3 : 1);
        int kx = rx ? (dxt ? 0 : 2) : (dxt ? 3 : 1);
        wt1k[idx] = wt1[((ci * 32 + co) * 4 + ky) * 4 + kx];
    } else if (gid < 32768 + 18432) {
        int j = gid - 32768;
        int co = j & 63, rest = j >> 6;
        int pos = rest % 9, ci = rest / 9;
        wdk[j] = wd[(co * C2 + ci) * 9 + pos];
    } else if (gid < 32768 + 18432 + 1024) {
        int j = gid - (32768 + 18432);
        int co = j & 1, tap = (j >> 1) & 3, ci = (j >> 3) & 31, par = j >> 8;
        int dyt = tap >> 1, dxt = tap & 1;
        int ry = par >> 1, rx = par & 1;
        int ky = ry ? (dyt ? 0 : 2) : (dyt ? 3 : 1);
        int kx = rx ? (dxt ? 0 : 2) : (dxt ? 3 : 1);
        wt2k[j] = wt2[((ci * 2 + co) * 4 + ky) * 4 + kx];
    }
}

// ---------------- Kernel C: 3x3 conv s1 p1 + bias + relu (reg-tiled) ----------------
// thread: 16 co x 4 x-positions. grid(3, cog=4, b=32)
__global__ __launch_bounds__(256) void k_convd(const float* __restrict__ mem2,
                                               const float* __restrict__ wdk,
                                               const float* __restrict__ bd,
                                               float* __restrict__ h1) {
    int i = blockIdx.x * blockDim.x + threadIdx.x;
    if (i >= 575) return;
    int ng = i % 23, m = i / 23;
    int n0 = ng * 4;
    int cog = blockIdx.y;
    int b = blockIdx.z;
    int co0 = cog * 16;
    float acc[16][4];
#pragma unroll
    for (int j = 0; j < 16; ++j) {
        float bv = bd[co0 + j];
        acc[j][0] = bv; acc[j][1] = bv; acc[j][2] = bv; acc[j][3] = bv;
    }
    bool lvL = (ng > 0), lvR = (n0 + 4 < W2);
    for (int ci = 0; ci < C2; ++ci) {
        const float* base = mem2 + (size_t)(b * C2 + ci) * (H2 * W2);
        const float* wc = wdk + (size_t)ci * 576 + co0;
#pragma unroll
        for (int ky = 0; ky < 3; ++ky) {
            int iy = m + ky - 1;
            float4 q = make_float4(0, 0, 0, 0);
            float l = 0.f, r = 0.f;
            if (iy >= 0 && iy < H2) {
                const float* row = base + iy * W2;
                q = *(const float4*)(row + n0);
                if (lvL) l = row[n0 - 1];
                if (lvR) r = row[n0 + 4];
            }
            const float* wk = wc + ky * 3 * 64;
#pragma unroll
            for (int j = 0; j < 16; ++j) {
                float wA = wk[j], wB = wk[64 + j], wC = wk[128 + j];
                acc[j][0] += l   * wA + q.x * wB + q.y * wC;
                acc[j][1] += q.x * wA + q.y * wB + q.z * wC;
                acc[j][2] += q.y * wA + q.z * wB + q.w * wC;
                acc[j][3] += q.z * wA + q.w * wB + r   * wC;
            }
        }
    }
    int sp = m * W2 + n0;
#pragma unroll
    for (int j = 0; j < 16; ++j) {
        float4 o;
        o.x = fmaxf(acc[j][0], 0.f); o.y = fmaxf(acc[j][1], 0.f);
        o.z = fmaxf(acc[j][2], 0.f); o.w = fmaxf(acc[j][3], 0.f);
        *(float4*)(h1 + (size_t)(b * CD + co0 + j) * (H2 * W2) + sp) = o;
    }
}

// ---------------- Kernel D: convT 4x4 s2 p1 (64->32), parity-decomposed ----------------
// thread: 16 co x 4 n-positions of one parity sub-grid. grid(3, par*2+cog=8, b=32)
__global__ __launch_bounds__(256) void k_convt1(const float* __restrict__ h1,
                                                const float* __restrict__ wt1k,
                                                const float* __restrict__ bt1,
                                                float* __restrict__ h2) {
    int i = blockIdx.x * blockDim.x + threadIdx.x;
    if (i >= 575) return;
    int ng = i % 23, m = i / 23;        // m in [0,25), sub-grid row
    int n0 = ng * 4;
    int y = blockIdx.y;
    int cog = y & 1;
    int par = y >> 1;
    int rx = par & 1, ry = par >> 1;
    int b = blockIdx.z;
    int co0 = cog * 16;
    float acc[16][4];
#pragma unroll
    for (int j = 0; j < 16; ++j) {
        float bv = bt1[co0 + j];
        acc[j][0] = bv; acc[j][1] = bv; acc[j][2] = bv; acc[j][3] = bv;
    }
    int iy1 = m + (ry ? 1 : -1);
    bool r1v = (iy1 >= 0) && (iy1 < H2);
    bool ev = rx ? (n0 + 4 < W2) : (ng > 0);
    const float* wb = wt1k + (size_t)par * 64 * 4 * 32 + co0;
    for (int ci = 0; ci < CD; ++ci) {
        const float* base = h1 + (size_t)(b * CD + ci) * (H2 * W2);
        const float* r0 = base + m * W2;
        float4 q0 = *(const float4*)(r0 + n0);
        float e0 = ev ? (rx ? r0[n0 + 4] : r0[n0 - 1]) : 0.f;
        float4 q1 = make_float4(0, 0, 0, 0);
        float e1 = 0.f;
        if (r1v) {
            const float* r1 = base + iy1 * W2;
            q1 = *(const float4*)(r1 + n0);
            e1 = ev ? (rx ? r1[n0 + 4] : r1[n0 - 1]) : 0.f;
        }
        // shifted windows (dx tap): rx=0 -> {e,q.x,q.y,q.z}; rx=1 -> {q.y,q.z,q.w,e}
        float s00 = rx ? q0.y : e0,  s01 = rx ? q0.z : q0.x;
        float s02 = rx ? q0.w : q0.y, s03 = rx ? e0 : q0.z;
        float s10 = rx ? q1.y : e1,  s11 = rx ? q1.z : q1.x;
        float s12 = rx ? q1.w : q1.y, s13 = rx ? e1 : q1.z;
        const float* wr = wb + (size_t)ci * 128;
#pragma unroll
        for (int j = 0; j < 16; ++j) {
            float w0 = wr[j], w1 = wr[32 + j], w2_ = wr[64 + j], w3 = wr[96 + j];
            acc[j][0] += q0.x * w0 + s00 * w1 + q1.x * w2_ + s10 * w3;
            acc[j][1] += q0.y * w0 + s01 * w1 + q1.y * w2_ + s11 * w3;
            acc[j][2] += q0.z * w0 + s02 * w1 + q1.z * w2_ + s12 * w3;
            acc[j][3] += q0.w * w0 + s03 * w1 + q1.w * w2_ + s13 * w3;
        }
    }
    int oy = 2 * m + ry;
#pragma unroll
    for (int j = 0; j < 16; ++j) {
        float* op = h2 + (size_t)(b * C2 + co0 + j) * (H1 * W1) + (size_t)oy * W1;
#pragma unroll
        for (int k = 0; k < 4; ++k)
            op[2 * (n0 + k) + rx] = fmaxf(acc[j][k], 0.f);
    }
}

// ---------------- Kernel E: convT 4x4 s2 p1 (32->2) + softplus, parity-decomposed ----------------
// thread: 2 co x 8 n-positions. grid(5, par=4, b=32)
__global__ __launch_bounds__(256) void k_convt2(const float* __restrict__ h2,
                                                const float* __restrict__ wt2k,
                                                const float* __restrict__ bt2,
                                                float* __restrict__ out) {
    int i = blockIdx.x * blockDim.x + threadIdx.x;
    if (i >= 1150) return;
    int ng = i % 23, m = i / 23;        // m in [0,50)
    int n0 = ng * 8;
    int par = blockIdx.y;
    int rx = par & 1, ry = par >> 1;
    int b = blockIdx.z;
    float a0[8], a1[8];
    float bv0 = bt2[0], bv1 = bt2[1];
#pragma unroll
    for (int k = 0; k < 8; ++k) { a0[k] = bv0; a1[k] = bv1; }
    int iy1 = m + (ry ? 1 : -1);
    bool r1v = (iy1 >= 0) && (iy1 < H1);
    bool ev = rx ? (n0 + 8 < W1) : (ng > 0);
    const float* wb = wt2k + (size_t)par * C2 * 8;
    for (int ci = 0; ci < C2; ++ci) {
        const float* base = h2 + (size_t)(b * C2 + ci) * (H1 * W1);
        const float* r0 = base + m * W1;
        float v[8], u[8];
        *(float4*)v = *(const float4*)(r0 + n0);
        *(float4*)(v + 4) = *(const float4*)(r0 + n0 + 4);
        float e0 = ev ? (rx ? r0[n0 + 8] : r0[n0 - 1]) : 0.f;
        float eu = 0.f;
        if (r1v) {
            const float* r1 = base + iy1 * W1;
            *(float4*)u = *(const float4*)(r1 + n0);
            *(float4*)(u + 4) = *(const float4*)(r1 + n0 + 4);
            eu = ev ? (rx ? r1[n0 + 8] : r1[n0 - 1]) : 0.f;
        } else {
#pragma unroll
            for (int k = 0; k < 8; ++k) u[k] = 0.f;
        }
        float sv[8], su[8];
#pragma unroll
        for (int k = 0; k < 8; ++k) {
            sv[k] = rx ? (k < 7 ? v[k + 1] : e0) : (k > 0 ? v[k - 1] : e0);
            su[k] = rx ? (k < 7 ? u[k + 1] : eu) : (k > 0 ? u[k - 1] : eu);
        }
        const float* wr = wb + ci * 8;
        float w00 = wr[0], w01 = wr[1], w10 = wr[2], w11 = wr[3];
        float w20 = wr[4], w21 = wr[5], w30 = wr[6], w31 = wr[7];
#pragma unroll
        for (int k = 0; k < 8; ++k) {
            a0[k] += v[k] * w00 + sv[k] * w10 + u[k] * w20 + su[k] * w30;
            a1[k] += v[k] * w01 + sv[k] * w11 + u[k] * w21 + su[k] * w31;
        }
    }
    int oy = 2 * m + ry;
    size_t base_o = (size_t)b * (H0 * W0) + (size_t)oy * W0;
#pragma unroll
    for (int k = 0; k < 8; ++k) {
        int ox = 2 * (n0 + k) + rx;
        float x0 = a0[k], x1 = a1[k];
        out[base_o + ox] = fmaxf(x0, 0.f) + log1pf(expf(-fabsf(x0)));
        out[(size_t)NB * H0 * W0 + base_o + ox] = fmaxf(x1, 0.f) + log1pf(expf(-fabsf(x1)));
    }
}

extern "C" void kernel_launch(void* const* d_in, const int* in_sizes, int n_in,
                              void* d_out, int out_size, void* d_ws, size_t ws_size,
                              hipStream_t stream) {
    const float* x   = (const float*)d_in[0];
    const float* w1  = (const float*)d_in[1];
    const float* w2  = (const float*)d_in[2];
    const float* wd  = (const float*)d_in[3];
    const float* bd  = (const float*)d_in[4];
    const float* wt1 = (const float*)d_in[5];
    const float* bt1 = (const float*)d_in[6];
    const float* wt2 = (const float*)d_in[7];
    const float* bt2 = (const float*)d_in[8];
    float* out = (float*)d_out;

    char* ws = (char*)d_ws;
    // workspace layout (bytes), total 75,366,400:
    //   s1m : [0, 9,420,800)           spikes, live snn1->snn2; then reused for repacked weights
    //   mem2: [9,420,800, 18,841,600)  live snn2->convd
    //   h1  : [18,841,600, 37,683,200) live convd->convt1
    //   h2  : [37,683,200, 75,366,400) live convt1->convt2
    //   xb  : overlays h2 slot (2.46 MB), dead after snn1 (before h2 written)
    //   wt1k/wdk/wt2k: overlay s1m slot, written by k_repack AFTER snn2 consumed s1m
    unsigned short* s1m = (unsigned short*)ws;
    float* mem2 = (float*)(ws + 9420800);
    float* h1   = (float*)(ws + 18841600);
    float* h2   = (float*)(ws + 37683200);
    unsigned long long* xb = (unsigned long long*)(ws + 37683200);
    float* wt1k = (float*)(ws + 0);        // 131072 B
    float* wdk  = (float*)(ws + 131072);   //  73728 B
    float* wt2k = (float*)(ws + 204800);   //   4096 B

    {
        long long nthreads = (long long)T_STEPS * NB * H0 * WPR * 64;
        int blocks = (int)((nthreads + 255) / 256);
        k_pack<<<blocks, 256, 0, stream>>>(x, xb);
    }
    {
        int n = NB * H1 * W1;
        k_snn1<<<(n + 255) / 256, 256, 0, stream>>>(xb, w1, s1m);
    }
    {
        int n = NB * H2 * W2;
        k_snn2<<<(n + 255) / 256, 256, 0, stream>>>(s1m, w2, mem2);
    }
    {
        int n = 32768 + 18432 + 1024;
        k_repack<<<(n + 255) / 256, 256, 0, stream>>>(wt1, wd, wt2, wt1k, wdk, wt2k);
    }
    {
        dim3 g(3, 4, NB);
        k_convd<<<g, 256, 0, stream>>>(mem2, wdk, bd, h1);
    }
    {
        dim3 g(3, 8, NB);
        k_convt1<<<g, 256, 0, stream>>>(h1, wt1k, bt1, h2);
    }
    {
        dim3 g(5, 4, NB);
        k_convt2<<<g, 256, 0, stream>>>(h2, wt2k, bt2, out);
    }
}

// Round 4
// 230.711 us; speedup vs baseline: 15.7900x; 1.6519x over previous
//
#include <hip/hip_runtime.h>
#include <hip/hip_bf16.h>
#include <cstddef>

// Shapes (fixed):
// x_seq: (T=16, B=32, 1, 100, 368) binary {0,1} fp32
// conv1: w1 (16,1,5,5) s2 p2   -> (32,16,50,184)
// conv2: w2 (32,16,3,3) s2 p1  -> (32,32,25,92)
// convd: wd (64,32,3,3) s1 p1  -> (32,64,25,92), relu        [MFMA bf16]
// convT1: wt1 (64,32,4,4) s2 p1 -> (32,32,50,184), relu      [MFMA bf16, parity-split]
// convT2: wt2 (32,2,4,4) s2 p1  -> (32,2,100,368), softplus  [VALU, bf16 reads]

#define T_STEPS 16
#define NB 32
#define H0 100
#define W0 368
#define C1 16
#define H1 50
#define W1 184
#define C2 32
#define H2 25
#define W2 92
#define CD 64
#define WPR 6
#define SITES2 2300   // 25*92
#define SITES1 9200   // 50*184

using f32x16 = __attribute__((ext_vector_type(16))) float;
using s16x8  = __attribute__((ext_vector_type(8))) short;

__device__ inline unsigned short f2bf(float f) {
    union { float f; unsigned int u; } v; v.f = f;
    unsigned int r = v.u + 0x7fffu + ((v.u >> 16) & 1u);  // RNE
    return (unsigned short)(r >> 16);
}
__device__ inline float bf2f(unsigned short u) {
    union { unsigned int u; float f; } v; v.u = ((unsigned int)u) << 16;
    return v.f;
}
__device__ inline unsigned int pk2(float a, float b) {
    return (unsigned int)f2bf(a) | ((unsigned int)f2bf(b) << 16);
}
__device__ inline s16x8 ld8(const void* p) { return *reinterpret_cast<const s16x8*>(p); }

// ---------------- Kernel P: bit-pack binary input ----------------
__global__ __launch_bounds__(256) void k_pack(const float* __restrict__ x,
                                              unsigned long long* __restrict__ xb) {
    long long gid = (long long)blockIdx.x * blockDim.x + threadIdx.x;
    long long widx = gid >> 6;
    int lane = (int)(gid & 63);
    const long long NWORDS = (long long)T_STEPS * NB * H0 * WPR;
    if (widx >= NWORDS) return;
    int wcol = (int)(widx % WPR);
    long long rowid = widx / WPR;
    int y = (int)(rowid % H0);
    long long tb = rowid / H0;
    int col = wcol * 64 + lane;
    float v = 0.f;
    if (col < W0) v = x[(tb * H0 + y) * W0 + col];
    unsigned long long mask = __ballot(v != 0.f);
    if (lane == 0) xb[widx] = mask;
}

// ---------------- Kernel A: conv1 + LIF over all 16 timesteps ----------------
__global__ __launch_bounds__(256) void k_snn1(const unsigned long long* __restrict__ xb,
                                              const float* __restrict__ w1,
                                              unsigned short* __restrict__ s1m) {
    __shared__ float sw[25 * C1]; // [k][c]
    for (int i = threadIdx.x; i < 25 * C1; i += blockDim.x) {
        int k = i >> 4, c = i & 15;
        sw[i] = w1[c * 25 + k];
    }
    __syncthreads();

    int idx = blockIdx.x * blockDim.x + threadIdx.x;
    const int NPOS = NB * H1 * W1;
    if (idx >= NPOS) return;
    int x1 = idx % W1;
    int tmp = idx / W1;
    int y1 = tmp % H1;
    int b  = tmp / H1;

    float m1[C1];
#pragma unroll
    for (int c = 0; c < C1; ++c) m1[c] = 0.f;

    const int iy0 = 2 * y1 - 2;
    const int ix0 = 2 * x1 - 2;
    const int wi = ix0 >> 6;
    const int s  = ix0 & 63;

    for (int t = 0; t < T_STEPS; ++t) {
#pragma unroll
        for (int c = 0; c < C1; ++c) m1[c] *= 0.5f;

        const unsigned long long* xp = xb + ((size_t)(t * NB + b) * H0) * WPR;
        unsigned int bits25 = 0;
#pragma unroll
        for (int ky = 0; ky < 5; ++ky) {
            int iy = iy0 + ky;
            if (iy < 0 || iy >= H0) continue;
            const unsigned long long* row = xp + (size_t)iy * WPR;
            unsigned long long a = (wi >= 0) ? row[wi] : 0ull;
            unsigned long long bw = (wi + 1 < WPR) ? row[wi + 1] : 0ull;
            unsigned long long chunk = a >> s;
            if (s) chunk |= (bw << (64 - s));
            bits25 |= ((unsigned int)chunk & 31u) << (5 * ky);
        }
        while (bits25) {
            int k = __ffs(bits25) - 1;
            bits25 &= bits25 - 1;
            const float* wk = &sw[k * C1];
#pragma unroll
            for (int c = 0; c < C1; ++c) m1[c] += wk[c];
        }
        unsigned int mask = 0;
#pragma unroll
        for (int c = 0; c < C1; ++c) {
            if (m1[c] >= 1.0f) { mask |= (1u << c); m1[c] = 0.f; }
        }
        s1m[(size_t)t * NPOS + idx] = (unsigned short)mask;
    }
}

// ---------------- Kernel B: conv2 + LIF; writes mem2 channel-last bf16 ----------------
__global__ __launch_bounds__(256) void k_snn2(const unsigned short* __restrict__ s1m,
                                              const float* __restrict__ w2,
                                              unsigned short* __restrict__ mem2bf) {
    __shared__ float sw[9 * C1 * 36];
    for (int i = threadIdx.x; i < 9 * C1 * C2; i += blockDim.x) {
        int c2 = i & 31;
        int r = i >> 5;
        int ci = r & 15;
        int pos = r >> 4;
        sw[r * 36 + c2] = w2[(c2 * C1 + ci) * 9 + pos];
    }
    __syncthreads();

    int idx = blockIdx.x * blockDim.x + threadIdx.x;
    const int NPOS = NB * H2 * W2;
    if (idx >= NPOS) return;
    int x2 = idx % W2;
    int tmp = idx / W2;
    int y2 = tmp % H2;
    int b  = tmp / H2;

    float m2[C2];
#pragma unroll
    for (int c = 0; c < C2; ++c) m2[c] = 0.f;

    const int S1POS = NB * H1 * W1;
    for (int t = 0; t < T_STEPS; ++t) {
#pragma unroll
        for (int c = 0; c < C2; ++c) m2[c] *= 0.5f;
        const unsigned short* spk = s1m + (size_t)t * S1POS + (size_t)b * (H1 * W1);
#pragma unroll
        for (int ky = 0; ky < 3; ++ky) {
            int iy = 2 * y2 + ky - 1;
            if (iy < 0 || iy >= H1) continue;
#pragma unroll
            for (int kx = 0; kx < 3; ++kx) {
                int ix = 2 * x2 + kx - 1;
                if (ix < 0 || ix >= W1) continue;
                unsigned int mask = spk[iy * W1 + ix];
                while (mask) {
                    int ci = __ffs(mask) - 1;
                    mask &= mask - 1;
                    const float* wrow = &sw[((ky * 3 + kx) * C1 + ci) * 36];
#pragma unroll
                    for (int c = 0; c < C2; ++c) m2[c] += wrow[c];
                }
            }
        }
#pragma unroll
        for (int c = 0; c < C2; ++c) {
            if (m2[c] >= 1.0f) m2[c] = 0.f;
        }
    }
    // channel-last bf16 write: [b][site][ci32]
    size_t sbase = ((size_t)b * SITES2 + (size_t)y2 * W2 + x2) * C2;
    uint4* dst = (uint4*)(mem2bf + sbase);
#pragma unroll
    for (int g = 0; g < 4; ++g) {
        uint4 u;
        u.x = pk2(m2[g * 8 + 0], m2[g * 8 + 1]);
        u.y = pk2(m2[g * 8 + 2], m2[g * 8 + 3]);
        u.z = pk2(m2[g * 8 + 4], m2[g * 8 + 5]);
        u.w = pk2(m2[g * 8 + 6], m2[g * 8 + 7]);
        dst[g] = u;
    }
}

// ---------------- Kernel R: repack weights (bf16 for MFMA; fp32 for convt2) ----------------
// wdb [co64][k288] bf16, k = (ky*3+kx)*32 + ci
// wt1b[par4][co32][k256] bf16, k = tap*64 + ci, tap=(ty<<1)|tx
// wt2k[par4][tap4][ci32][co2] fp32
__global__ __launch_bounds__(256) void k_repackb(const float* __restrict__ wd,
                                                 const float* __restrict__ wt1,
                                                 const float* __restrict__ wt2,
                                                 unsigned short* __restrict__ wdb,
                                                 unsigned short* __restrict__ wt1b,
                                                 float* __restrict__ wt2k) {
    int gid = blockIdx.x * blockDim.x + threadIdx.x;
    if (gid < 64 * 288) {
        int co = gid / 288, k = gid % 288;
        int tap = k >> 5, ci = k & 31;
        wdb[gid] = f2bf(wd[((size_t)co * C2 + ci) * 9 + tap]);
    } else if (gid < 64 * 288 + 4 * 32 * 256) {
        int j = gid - 64 * 288;
        int par = j >> 13, co = (j >> 8) & 31, k = j & 255;
        int tap = k >> 6, ci = k & 63;
        int ty = tap >> 1, tx = tap & 1;
        int ry = par >> 1, rx = par & 1;
        int ky = ry ? (ty ? 0 : 2) : (ty ? 3 : 1);
        int kx = rx ? (tx ? 0 : 2) : (tx ? 3 : 1);
        wt1b[j] = f2bf(wt1[(((size_t)ci * 32 + co) * 4 + ky) * 4 + kx]);
    } else if (gid < 64 * 288 + 4 * 32 * 256 + 1024) {
        int j = gid - (64 * 288 + 4 * 32 * 256);
        int par = j >> 8, tap = (j >> 6) & 3, ci = (j >> 1) & 31, co = j & 1;
        int ty = tap >> 1, tx = tap & 1;
        int ry = par >> 1, rx = par & 1;
        int ky = ry ? (ty ? 0 : 2) : (ty ? 3 : 1);
        int kx = rx ? (tx ? 0 : 2) : (tx ? 3 : 1);
        wt2k[j] = wt2[(((size_t)ci * 2 + co) * 4 + ky) * 4 + kx];
    }
}

// ---------------- Kernel C: convd via MFMA ----------------
// wave: 64co x 32 sites; grid(18, 1, 32)
__global__ __launch_bounds__(256) void k_convd(const unsigned short* __restrict__ mem2bf,
                                               const unsigned short* __restrict__ wdb,
                                               const float* __restrict__ bd,
                                               unsigned short* __restrict__ h1bf) {
    int wave = threadIdx.x >> 6;
    int lane = threadIdx.x & 63;
    int col = lane & 31, hi = lane >> 5;
    int b = blockIdx.z;
    int n0 = (blockIdx.x * 4 + wave) * 32;
    int site = n0 + col;
    bool sval = site < SITES2;
    int sc = sval ? site : 0;
    int yy = sc / W2, xx = sc % W2;

    const char* ibase = (const char*)(mem2bf + (size_t)b * SITES2 * C2);
    int toff[9];
    bool tval[9];
#pragma unroll
    for (int ky = 0; ky < 3; ++ky)
#pragma unroll
        for (int kx = 0; kx < 3; ++kx) {
            int iy = yy + ky - 1, ix = xx + kx - 1;
            bool v = sval && iy >= 0 && iy < H2 && ix >= 0 && ix < W2;
            tval[ky * 3 + kx] = v;
            toff[ky * 3 + kx] = (iy * W2 + ix) * (C2 * 2);
        }

    const char* abase = (const char*)wdb;
    f32x16 acc0 = {}, acc1 = {};
    const s16x8 zero = {0, 0, 0, 0, 0, 0, 0, 0};
#pragma unroll
    for (int s = 0; s < 18; ++s) {
        int tap = s >> 1;
        int boff = (s & 1) * 32 + hi * 16;
        s16x8 bf = tval[tap] ? ld8(ibase + toff[tap] + boff) : zero;
        s16x8 a0 = ld8(abase + col * 576 + s * 32 + hi * 16);
        s16x8 a1 = ld8(abase + (col + 32) * 576 + s * 32 + hi * 16);
        acc0 = __builtin_amdgcn_mfma_f32_32x32x16_bf16(a0, bf, acc0, 0, 0, 0);
        acc1 = __builtin_amdgcn_mfma_f32_32x32x16_bf16(a1, bf, acc1, 0, 0, 0);
    }
    if (!sval) return;
    char* obase = (char*)(h1bf + ((size_t)b * SITES2 + site) * CD);
#pragma unroll
    for (int t = 0; t < 2; ++t) {
        const f32x16& ac = t ? acc1 : acc0;
#pragma unroll
        for (int q = 0; q < 4; ++q) {
            int co = t * 32 + 8 * q + 4 * hi;
            float v0 = fmaxf(ac[4 * q + 0] + bd[co + 0], 0.f);
            float v1 = fmaxf(ac[4 * q + 1] + bd[co + 1], 0.f);
            float v2 = fmaxf(ac[4 * q + 2] + bd[co + 2], 0.f);
            float v3 = fmaxf(ac[4 * q + 3] + bd[co + 3], 0.f);
            uint2 u; u.x = pk2(v0, v1); u.y = pk2(v2, v3);
            *(uint2*)(obase + co * 2) = u;
        }
    }
}

// ---------------- Kernel D: convt1 via MFMA, parity-split ----------------
// wave: 32co x 64 sites (2 n-tiles); grid(9, par=4, 32)
__global__ __launch_bounds__(256) void k_convt1(const unsigned short* __restrict__ h1bf,
                                                const unsigned short* __restrict__ wt1b,
                                                const float* __restrict__ bt1,
                                                unsigned short* __restrict__ h2bf) {
    int wave = threadIdx.x >> 6;
    int lane = threadIdx.x & 63;
    int col = lane & 31, hi = lane >> 5;
    int par = blockIdx.y;
    int ry = par >> 1, rx = par & 1;
    int b = blockIdx.z;
    int n0 = (blockIdx.x * 4 + wave) * 64;

    const char* ibase = (const char*)(h1bf + (size_t)b * SITES2 * CD);
    int toff[2][4];
    bool tval[2][4];
    int mm[2], nn[2];
    bool sv[2];
#pragma unroll
    for (int j = 0; j < 2; ++j) {
        int site = n0 + j * 32 + col;
        sv[j] = site < SITES2;
        int sc = sv[j] ? site : 0;
        int m = sc / W2, n = sc % W2;
        mm[j] = m; nn[j] = n;
        int iy1 = m + (ry ? 1 : -1);
        int ix1 = n + (rx ? 1 : -1);
        bool y1v = iy1 >= 0 && iy1 < H2;
        bool x1v = ix1 >= 0 && ix1 < W2;
#pragma unroll
        for (int t = 0; t < 4; ++t) {
            int ty = t >> 1, tx = t & 1;
            int iy = ty ? iy1 : m;
            int ix = tx ? ix1 : n;
            tval[j][t] = sv[j] && (ty ? y1v : true) && (tx ? x1v : true);
            toff[j][t] = (iy * W2 + ix) * (CD * 2);
        }
    }

    const char* abase = (const char*)(wt1b + (size_t)par * 32 * 256);
    f32x16 acc0 = {}, acc1 = {};
    const s16x8 zero = {0, 0, 0, 0, 0, 0, 0, 0};
#pragma unroll
    for (int s = 0; s < 16; ++s) {
        int tap = s >> 2;
        int boff = (s & 3) * 32 + hi * 16;
        s16x8 b0 = tval[0][tap] ? ld8(ibase + toff[0][tap] + boff) : zero;
        s16x8 b1 = tval[1][tap] ? ld8(ibase + toff[1][tap] + boff) : zero;
        s16x8 a = ld8(abase + col * 512 + s * 32 + hi * 16);
        acc0 = __builtin_amdgcn_mfma_f32_32x32x16_bf16(a, b0, acc0, 0, 0, 0);
        acc1 = __builtin_amdgcn_mfma_f32_32x32x16_bf16(a, b1, acc1, 0, 0, 0);
    }
#pragma unroll
    for (int j = 0; j < 2; ++j) {
        if (!sv[j]) continue;
        const f32x16& ac = j ? acc1 : acc0;
        int oy = 2 * mm[j] + ry, ox = 2 * nn[j] + rx;
        char* obase = (char*)(h2bf + ((size_t)b * SITES1 + (size_t)oy * W1 + ox) * C2);
#pragma unroll
        for (int q = 0; q < 4; ++q) {
            int co = 8 * q + 4 * hi;
            float v0 = fmaxf(ac[4 * q + 0] + bt1[co + 0], 0.f);
            float v1 = fmaxf(ac[4 * q + 1] + bt1[co + 1], 0.f);
            float v2 = fmaxf(ac[4 * q + 2] + bt1[co + 2], 0.f);
            float v3 = fmaxf(ac[4 * q + 3] + bt1[co + 3], 0.f);
            uint2 u; u.x = pk2(v0, v1); u.y = pk2(v2, v3);
            *(uint2*)(obase + co * 2) = u;
        }
    }
}

// ---------------- Kernel E: convt2 VALU, bf16 channel-last input ----------------
// grid(36, par=4, 32); thread per sub-grid site
__global__ __launch_bounds__(256) void k_convt2(const unsigned short* __restrict__ h2bf,
                                                const float* __restrict__ wt2k,
                                                const float* __restrict__ bt2,
                                                float* __restrict__ out) {
    int i = blockIdx.x * blockDim.x + threadIdx.x;
    if (i >= SITES1) return;
    int par = blockIdx.y;
    int ry = par >> 1, rx = par & 1;
    int b = blockIdx.z;
    int m = i / W1, n = i % W1;
    int iy1 = m + (ry ? 1 : -1);
    int ix1 = n + (rx ? 1 : -1);
    bool y1v = iy1 >= 0 && iy1 < H1;
    bool x1v = ix1 >= 0 && ix1 < W1;

    float a0 = bt2[0], a1 = bt2[1];
    const unsigned short* ib = h2bf + (size_t)b * SITES1 * C2;
#pragma unroll
    for (int t = 0; t < 4; ++t) {
        int ty = t >> 1, tx = t & 1;
        if ((ty && !y1v) || (tx && !x1v)) continue;
        int iy = ty ? iy1 : m;
        int ix = tx ? ix1 : n;
        const unsigned short* p = ib + ((size_t)iy * W1 + ix) * C2;
        const float* w = wt2k + ((size_t)par * 4 + t) * 64;
#pragma unroll
        for (int g = 0; g < 4; ++g) {
            s16x8 v8 = ld8(p + g * 8);
#pragma unroll
            for (int e = 0; e < 8; ++e) {
                float v = bf2f((unsigned short)v8[e]);
                int ci = g * 8 + e;
                a0 += v * w[2 * ci];
                a1 += v * w[2 * ci + 1];
            }
        }
    }
    int oy = 2 * m + ry, ox = 2 * n + rx;
    size_t base_o = (size_t)b * (H0 * W0) + (size_t)oy * W0 + ox;
    out[base_o] = fmaxf(a0, 0.f) + log1pf(expf(-fabsf(a0)));
    out[(size_t)NB * H0 * W0 + base_o] = fmaxf(a1, 0.f) + log1pf(expf(-fabsf(a1)));
}

extern "C" void kernel_launch(void* const* d_in, const int* in_sizes, int n_in,
                              void* d_out, int out_size, void* d_ws, size_t ws_size,
                              hipStream_t stream) {
    const float* x   = (const float*)d_in[0];
    const float* w1  = (const float*)d_in[1];
    const float* w2  = (const float*)d_in[2];
    const float* wd  = (const float*)d_in[3];
    const float* bd  = (const float*)d_in[4];
    const float* wt1 = (const float*)d_in[5];
    const float* bt1 = (const float*)d_in[6];
    const float* wt2 = (const float*)d_in[7];
    const float* bt2 = (const float*)d_in[8];
    float* out = (float*)d_out;

    char* ws = (char*)d_ws;
    // workspace (bytes):
    unsigned short* s1m    = (unsigned short*)(ws);              //  9,420,800
    unsigned short* mem2bf = (unsigned short*)(ws + 9420800);    //  4,710,400
    unsigned short* h1bf   = (unsigned short*)(ws + 14131200);   //  9,420,800
    unsigned short* h2bf   = (unsigned short*)(ws + 23552000);   // 18,841,600
    unsigned long long* xb = (unsigned long long*)(ws + 42393600); // 2,457,600
    unsigned short* wdb    = (unsigned short*)(ws + 44851200);   //     36,864
    unsigned short* wt1b   = (unsigned short*)(ws + 44888064);   //     65,536
    float* wt2k            = (float*)(ws + 44953600);            //      4,096

    {
        long long nthreads = (long long)T_STEPS * NB * H0 * WPR * 64;
        int blocks = (int)((nthreads + 255) / 256);
        k_pack<<<blocks, 256, 0, stream>>>(x, xb);
    }
    {
        int n = NB * H1 * W1;
        k_snn1<<<(n + 255) / 256, 256, 0, stream>>>(xb, w1, s1m);
    }
    {
        int n = NB * H2 * W2;
        k_snn2<<<(n + 255) / 256, 256, 0, stream>>>(s1m, w2, mem2bf);
    }
    {
        int n = 64 * 288 + 4 * 32 * 256 + 1024; // 52224
        k_repackb<<<(n + 255) / 256, 256, 0, stream>>>(wd, wt1, wt2, wdb, wt1b, wt2k);
    }
    {
        dim3 g(18, 1, NB);
        k_convd<<<g, 256, 0, stream>>>(mem2bf, wdb, bd, h1bf);
    }
    {
        dim3 g(9, 4, NB);
        k_convt1<<<g, 256, 0, stream>>>(h1bf, wt1b, bt1, h2bf);
    }
    {
        dim3 g(36, 4, NB);
        k_convt2<<<g, 256, 0, stream>>>(h2bf, wt2k, bt2, out);
    }
}

// Round 5
// 207.405 us; speedup vs baseline: 17.5643x; 1.1124x over previous
//
#include <hip/hip_runtime.h>
#include <hip/hip_bf16.h>
#include <cstddef>

// Shapes (fixed):
// x_seq: (T=16, B=32, 1, 100, 368) binary {0,1} fp32
// conv1: w1 (16,1,5,5) s2 p2   -> (32,16,50,184)
// conv2: w2 (32,16,3,3) s2 p1  -> (32,32,25,92)   [MFMA bf16 3-term split, LIF in acc]
// convd: wd (64,32,3,3) s1 p1  -> (32,64,25,92), relu        [MFMA bf16]
// convT1: wt1 (64,32,4,4) s2 p1 -> (32,32,50,184), relu      [MFMA bf16, parity-split]
// convT2: wt2 (32,2,4,4) s2 p1  -> (32,2,100,368), softplus  [VALU, bf16 reads]

#define T_STEPS 16
#define NB 32
#define H0 100
#define W0 368
#define C1 16
#define H1 50
#define W1 184
#define C2 32
#define H2 25
#define W2 92
#define CD 64
#define WPR 6
#define SITES2 2300   // 25*92
#define SITES1 9200   // 50*184

using f32x16 = __attribute__((ext_vector_type(16))) float;
using s16x8  = __attribute__((ext_vector_type(8))) short;

__device__ inline unsigned short f2bf(float f) {
    union { float f; unsigned int u; } v; v.f = f;
    unsigned int r = v.u + 0x7fffu + ((v.u >> 16) & 1u);  // RNE
    return (unsigned short)(r >> 16);
}
__device__ inline float bf2f(unsigned short u) {
    union { unsigned int u; float f; } v; v.u = ((unsigned int)u) << 16;
    return v.f;
}
__device__ inline unsigned int pk2(float a, float b) {
    return (unsigned int)f2bf(a) | ((unsigned int)f2bf(b) << 16);
}
__device__ inline s16x8 ld8(const void* p) { return *reinterpret_cast<const s16x8*>(p); }

// ---------------- Kernel P: bit-pack binary input ----------------
__global__ __launch_bounds__(256) void k_pack(const float* __restrict__ x,
                                              unsigned long long* __restrict__ xb) {
    long long gid = (long long)blockIdx.x * blockDim.x + threadIdx.x;
    long long widx = gid >> 6;
    int lane = (int)(gid & 63);
    const long long NWORDS = (long long)T_STEPS * NB * H0 * WPR;
    if (widx >= NWORDS) return;
    int wcol = (int)(widx % WPR);
    long long rowid = widx / WPR;
    int y = (int)(rowid % H0);
    long long tb = rowid / H0;
    int col = wcol * 64 + lane;
    float v = 0.f;
    if (col < W0) v = x[(tb * H0 + y) * W0 + col];
    unsigned long long mask = __ballot(v != 0.f);
    if (lane == 0) xb[widx] = mask;
}

// ---------------- Kernel A: conv1 + LIF over all 16 timesteps ----------------
__global__ __launch_bounds__(256) void k_snn1(const unsigned long long* __restrict__ xb,
                                              const float* __restrict__ w1,
                                              unsigned short* __restrict__ s1m) {
    __shared__ float sw[25 * C1]; // [k][c]
    for (int i = threadIdx.x; i < 25 * C1; i += blockDim.x) {
        int k = i >> 4, c = i & 15;
        sw[i] = w1[c * 25 + k];
    }
    __syncthreads();

    int idx = blockIdx.x * blockDim.x + threadIdx.x;
    const int NPOS = NB * H1 * W1;
    if (idx >= NPOS) return;
    int x1 = idx % W1;
    int tmp = idx / W1;
    int y1 = tmp % H1;
    int b  = tmp / H1;

    float m1[C1];
#pragma unroll
    for (int c = 0; c < C1; ++c) m1[c] = 0.f;

    const int iy0 = 2 * y1 - 2;
    const int ix0 = 2 * x1 - 2;
    const int wi = ix0 >> 6;
    const int s  = ix0 & 63;

    for (int t = 0; t < T_STEPS; ++t) {
#pragma unroll
        for (int c = 0; c < C1; ++c) m1[c] *= 0.5f;

        const unsigned long long* xp = xb + ((size_t)(t * NB + b) * H0) * WPR;
        unsigned int bits25 = 0;
#pragma unroll
        for (int ky = 0; ky < 5; ++ky) {
            int iy = iy0 + ky;
            if (iy < 0 || iy >= H0) continue;
            const unsigned long long* row = xp + (size_t)iy * WPR;
            unsigned long long a = (wi >= 0) ? row[wi] : 0ull;
            unsigned long long bw = (wi + 1 < WPR) ? row[wi + 1] : 0ull;
            unsigned long long chunk = a >> s;
            if (s) chunk |= (bw << (64 - s));
            bits25 |= ((unsigned int)chunk & 31u) << (5 * ky);
        }
        while (bits25) {
            int k = __ffs(bits25) - 1;
            bits25 &= bits25 - 1;
            const float* wk = &sw[k * C1];
#pragma unroll
            for (int c = 0; c < C1; ++c) m1[c] += wk[c];
        }
        unsigned int mask = 0;
#pragma unroll
        for (int c = 0; c < C1; ++c) {
            if (m1[c] >= 1.0f) { mask |= (1u << c); m1[c] = 0.f; }
        }
        s1m[(size_t)t * NPOS + idx] = (unsigned short)mask;
    }
}

// ---------------- Kernel B: conv2+LIF fused MFMA over 16 timesteps ----------------
// wave = 32co x 32 sites; m2 state lives in the f32x16 accumulator.
// Spikes expanded from uint16 masks via 256-entry byte->8xbf16 LDS LUT.
// Weights: 3-term bf16 split (exact to < fp32 ulp).
__global__ __launch_bounds__(256) void k_snn2(const unsigned short* __restrict__ s1m,
                                              const unsigned short* __restrict__ w2b3,
                                              unsigned short* __restrict__ mem2bf) {
    __shared__ uint4 lut[256];
    {
        int m = (int)threadIdx.x;  // exactly 256 threads
        unsigned int wv[4];
#pragma unroll
        for (int h = 0; h < 4; ++h) {
            unsigned int lo = (m >> (2 * h)) & 1u, hb = (m >> (2 * h + 1)) & 1u;
            wv[h] = (lo ? 0x3F80u : 0u) | (hb ? 0x3F800000u : 0u);
        }
        lut[m] = make_uint4(wv[0], wv[1], wv[2], wv[3]);
    }
    __syncthreads();

    int wave = threadIdx.x >> 6;
    int lane = threadIdx.x & 63;
    int col = lane & 31, hi = lane >> 5;
    int gsite = (blockIdx.x * 4 + wave) * 32 + col;   // 0..73599 exact
    int b = gsite / SITES2;
    int rest = gsite % SITES2;
    int y2 = rest / W2, x2 = rest % W2;

    // tap validity/offsets (u16 index units within one (t,b) spike plane)
    int toff[9]; bool tval[9];
#pragma unroll
    for (int ky = 0; ky < 3; ++ky)
#pragma unroll
        for (int kx = 0; kx < 3; ++kx) {
            int iy = 2 * y2 + ky - 1, ix = 2 * x2 + kx - 1;
            tval[ky * 3 + kx] = iy >= 0 && iy < H1 && ix >= 0 && ix < W1;
            toff[ky * 3 + kx] = iy * W1 + ix;
        }

    // hoist all 27 A fragments (3 terms x 9 k-steps)
    const char* ab = (const char*)w2b3;
    s16x8 a0[9], a1[9], a2[9];
#pragma unroll
    for (int s = 0; s < 9; ++s) {
        int ko = (s * 16 + hi * 8) * 2;
        a0[s] = ld8(ab + (col * 144) * 2 + ko);
        a1[s] = ld8(ab + ((32 + col) * 144) * 2 + ko);
        a2[s] = ld8(ab + ((64 + col) * 144) * 2 + ko);
    }

    f32x16 acc = {};   // m2 state
    int hsh = hi * 8;

    for (int t = 0; t < T_STEPS; ++t) {
        const unsigned short* spk = s1m + (size_t)t * (NB * H1 * W1) + (size_t)b * (H1 * W1);
        unsigned int msk[9];
#pragma unroll
        for (int i = 0; i < 9; ++i)
            msk[i] = tval[i] ? (unsigned int)spk[toff[i]] : 0u;

        // decay
#pragma unroll
        for (int e = 0; e < 16; ++e) acc[e] *= 0.5f;

#pragma unroll
        for (int s = 0; s < 9; ++s) {
            unsigned int byte = (msk[s] >> hsh) & 0xFFu;
            s16x8 bf = *reinterpret_cast<const s16x8*>(&lut[byte]);
            acc = __builtin_amdgcn_mfma_f32_32x32x16_bf16(a0[s], bf, acc, 0, 0, 0);
            acc = __builtin_amdgcn_mfma_f32_32x32x16_bf16(a1[s], bf, acc, 0, 0, 0);
            acc = __builtin_amdgcn_mfma_f32_32x32x16_bf16(a2[s], bf, acc, 0, 0, 0);
        }
        // threshold + reset
#pragma unroll
        for (int e = 0; e < 16; ++e) {
            float v = acc[e];
            acc[e] = (v >= 1.0f) ? 0.f : v;
        }
    }

    // write mem2 channel-last bf16: [gsite][ci32]; row(co) = (r&3)+8*(r>>2)+4*hi
    char* obase = (char*)(mem2bf + (size_t)gsite * C2);
#pragma unroll
    for (int q = 0; q < 4; ++q) {
        int co = 8 * q + 4 * hi;
        uint2 u;
        u.x = pk2(acc[4 * q + 0], acc[4 * q + 1]);
        u.y = pk2(acc[4 * q + 2], acc[4 * q + 3]);
        *(uint2*)(obase + co * 2) = u;
    }
}

// ---------------- Kernel R: repack weights ----------------
// wdb [co64][k288] bf16, k = tap*32+ci ; wt1b[par4][co32][k256] bf16, k = tap*64+ci
// wt2k[par4][tap4][ci32][co2] fp32 ; w2b3[term3][co32][k144] bf16, k = tap*16+ci
__global__ __launch_bounds__(256) void k_repackb(const float* __restrict__ wd,
                                                 const float* __restrict__ wt1,
                                                 const float* __restrict__ wt2,
                                                 const float* __restrict__ w2,
                                                 unsigned short* __restrict__ wdb,
                                                 unsigned short* __restrict__ wt1b,
                                                 float* __restrict__ wt2k,
                                                 unsigned short* __restrict__ w2b3) {
    int gid = blockIdx.x * blockDim.x + threadIdx.x;
    if (gid < 64 * 288) {
        int co = gid / 288, k = gid % 288;
        int tap = k >> 5, ci = k & 31;
        wdb[gid] = f2bf(wd[((size_t)co * C2 + ci) * 9 + tap]);
    } else if (gid < 64 * 288 + 4 * 32 * 256) {
        int j = gid - 64 * 288;
        int par = j >> 13, co = (j >> 8) & 31, k = j & 255;
        int tap = k >> 6, ci = k & 63;
        int ty = tap >> 1, tx = tap & 1;
        int ry = par >> 1, rx = par & 1;
        int ky = ry ? (ty ? 0 : 2) : (ty ? 3 : 1);
        int kx = rx ? (tx ? 0 : 2) : (tx ? 3 : 1);
        wt1b[j] = f2bf(wt1[(((size_t)ci * 32 + co) * 4 + ky) * 4 + kx]);
    } else if (gid < 64 * 288 + 4 * 32 * 256 + 1024) {
        int j = gid - (64 * 288 + 4 * 32 * 256);
        int par = j >> 8, tap = (j >> 6) & 3, ci = (j >> 1) & 31, co = j & 1;
        int ty = tap >> 1, tx = tap & 1;
        int ry = par >> 1, rx = par & 1;
        int ky = ry ? (ty ? 0 : 2) : (ty ? 3 : 1);
        int kx = rx ? (tx ? 0 : 2) : (tx ? 3 : 1);
        wt2k[j] = wt2[(((size_t)ci * 2 + co) * 4 + ky) * 4 + kx];
    } else if (gid < 64 * 288 + 4 * 32 * 256 + 1024 + 3 * 32 * 144) {
        int j = gid - (64 * 288 + 4 * 32 * 256 + 1024);
        int p = j / 4608, rem = j % 4608;
        int co = rem / 144, k = rem % 144;
        int tap = k / 16, ci = k % 16;
        float w = w2[((size_t)co * C1 + ci) * 9 + tap];
        unsigned short b0 = f2bf(w);
        float r1 = w - bf2f(b0);
        unsigned short b1 = f2bf(r1);
        float r2 = r1 - bf2f(b1);
        unsigned short b2 = f2bf(r2);
        w2b3[j] = (p == 0) ? b0 : (p == 1) ? b1 : b2;
    }
}

// ---------------- Kernel C: convd via MFMA ----------------
__global__ __launch_bounds__(256) void k_convd(const unsigned short* __restrict__ mem2bf,
                                               const unsigned short* __restrict__ wdb,
                                               const float* __restrict__ bd,
                                               unsigned short* __restrict__ h1bf) {
    int wave = threadIdx.x >> 6;
    int lane = threadIdx.x & 63;
    int col = lane & 31, hi = lane >> 5;
    int b = blockIdx.z;
    int n0 = (blockIdx.x * 4 + wave) * 32;
    int site = n0 + col;
    bool sval = site < SITES2;
    int sc = sval ? site : 0;
    int yy = sc / W2, xx = sc % W2;

    const char* ibase = (const char*)(mem2bf + (size_t)b * SITES2 * C2);
    int toff[9];
    bool tval[9];
#pragma unroll
    for (int ky = 0; ky < 3; ++ky)
#pragma unroll
        for (int kx = 0; kx < 3; ++kx) {
            int iy = yy + ky - 1, ix = xx + kx - 1;
            bool v = sval && iy >= 0 && iy < H2 && ix >= 0 && ix < W2;
            tval[ky * 3 + kx] = v;
            toff[ky * 3 + kx] = (iy * W2 + ix) * (C2 * 2);
        }

    const char* abase = (const char*)wdb;
    f32x16 acc0 = {}, acc1 = {};
    const s16x8 zero = {0, 0, 0, 0, 0, 0, 0, 0};
#pragma unroll
    for (int s = 0; s < 18; ++s) {
        int tap = s >> 1;
        int boff = (s & 1) * 32 + hi * 16;
        s16x8 bf = tval[tap] ? ld8(ibase + toff[tap] + boff) : zero;
        s16x8 a0 = ld8(abase + col * 576 + s * 32 + hi * 16);
        s16x8 a1 = ld8(abase + (col + 32) * 576 + s * 32 + hi * 16);
        acc0 = __builtin_amdgcn_mfma_f32_32x32x16_bf16(a0, bf, acc0, 0, 0, 0);
        acc1 = __builtin_amdgcn_mfma_f32_32x32x16_bf16(a1, bf, acc1, 0, 0, 0);
    }
    if (!sval) return;
    char* obase = (char*)(h1bf + ((size_t)b * SITES2 + site) * CD);
#pragma unroll
    for (int t = 0; t < 2; ++t) {
        const f32x16& ac = t ? acc1 : acc0;
#pragma unroll
        for (int q = 0; q < 4; ++q) {
            int co = t * 32 + 8 * q + 4 * hi;
            float v0 = fmaxf(ac[4 * q + 0] + bd[co + 0], 0.f);
            float v1 = fmaxf(ac[4 * q + 1] + bd[co + 1], 0.f);
            float v2 = fmaxf(ac[4 * q + 2] + bd[co + 2], 0.f);
            float v3 = fmaxf(ac[4 * q + 3] + bd[co + 3], 0.f);
            uint2 u; u.x = pk2(v0, v1); u.y = pk2(v2, v3);
            *(uint2*)(obase + co * 2) = u;
        }
    }
}

// ---------------- Kernel D: convt1 via MFMA, parity-split ----------------
__global__ __launch_bounds__(256) void k_convt1(const unsigned short* __restrict__ h1bf,
                                                const unsigned short* __restrict__ wt1b,
                                                const float* __restrict__ bt1,
                                                unsigned short* __restrict__ h2bf) {
    int wave = threadIdx.x >> 6;
    int lane = threadIdx.x & 63;
    int col = lane & 31, hi = lane >> 5;
    int par = blockIdx.y;
    int ry = par >> 1, rx = par & 1;
    int b = blockIdx.z;
    int n0 = (blockIdx.x * 4 + wave) * 64;

    const char* ibase = (const char*)(h1bf + (size_t)b * SITES2 * CD);
    int toff[2][4];
    bool tval[2][4];
    int mm[2], nn[2];
    bool sv[2];
#pragma unroll
    for (int j = 0; j < 2; ++j) {
        int site = n0 + j * 32 + col;
        sv[j] = site < SITES2;
        int sc = sv[j] ? site : 0;
        int m = sc / W2, n = sc % W2;
        mm[j] = m; nn[j] = n;
        int iy1 = m + (ry ? 1 : -1);
        int ix1 = n + (rx ? 1 : -1);
        bool y1v = iy1 >= 0 && iy1 < H2;
        bool x1v = ix1 >= 0 && ix1 < W2;
#pragma unroll
        for (int t = 0; t < 4; ++t) {
            int ty = t >> 1, tx = t & 1;
            int iy = ty ? iy1 : m;
            int ix = tx ? ix1 : n;
            tval[j][t] = sv[j] && (ty ? y1v : true) && (tx ? x1v : true);
            toff[j][t] = (iy * W2 + ix) * (CD * 2);
        }
    }

    const char* abase = (const char*)(wt1b + (size_t)par * 32 * 256);
    f32x16 acc0 = {}, acc1 = {};
    const s16x8 zero = {0, 0, 0, 0, 0, 0, 0, 0};
#pragma unroll
    for (int s = 0; s < 16; ++s) {
        int tap = s >> 2;
        int boff = (s & 3) * 32 + hi * 16;
        s16x8 b0 = tval[0][tap] ? ld8(ibase + toff[0][tap] + boff) : zero;
        s16x8 b1 = tval[1][tap] ? ld8(ibase + toff[1][tap] + boff) : zero;
        s16x8 a = ld8(abase + col * 512 + s * 32 + hi * 16);
        acc0 = __builtin_amdgcn_mfma_f32_32x32x16_bf16(a, b0, acc0, 0, 0, 0);
        acc1 = __builtin_amdgcn_mfma_f32_32x32x16_bf16(a, b1, acc1, 0, 0, 0);
    }
#pragma unroll
    for (int j = 0; j < 2; ++j) {
        if (!sv[j]) continue;
        const f32x16& ac = j ? acc1 : acc0;
        int oy = 2 * mm[j] + ry, ox = 2 * nn[j] + rx;
        char* obase = (char*)(h2bf + ((size_t)b * SITES1 + (size_t)oy * W1 + ox) * C2);
#pragma unroll
        for (int q = 0; q < 4; ++q) {
            int co = 8 * q + 4 * hi;
            float v0 = fmaxf(ac[4 * q + 0] + bt1[co + 0], 0.f);
            float v1 = fmaxf(ac[4 * q + 1] + bt1[co + 1], 0.f);
            float v2 = fmaxf(ac[4 * q + 2] + bt1[co + 2], 0.f);
            float v3 = fmaxf(ac[4 * q + 3] + bt1[co + 3], 0.f);
            uint2 u; u.x = pk2(v0, v1); u.y = pk2(v2, v3);
            *(uint2*)(obase + co * 2) = u;
        }
    }
}

// ---------------- Kernel E: convt2 VALU, bf16 channel-last input ----------------
__global__ __launch_bounds__(256) void k_convt2(const unsigned short* __restrict__ h2bf,
                                                const float* __restrict__ wt2k,
                                                const float* __restrict__ bt2,
                                                float* __restrict__ out) {
    int i = blockIdx.x * blockDim.x + threadIdx.x;
    if (i >= SITES1) return;
    int par = blockIdx.y;
    int ry = par >> 1, rx = par & 1;
    int b = blockIdx.z;
    int m = i / W1, n = i % W1;
    int iy1 = m + (ry ? 1 : -1);
    int ix1 = n + (rx ? 1 : -1);
    bool y1v = iy1 >= 0 && iy1 < H1;
    bool x1v = ix1 >= 0 && ix1 < W1;

    float a0 = bt2[0], a1 = bt2[1];
    const unsigned short* ib = h2bf + (size_t)b * SITES1 * C2;
#pragma unroll
    for (int t = 0; t < 4; ++t) {
        int ty = t >> 1, tx = t & 1;
        if ((ty && !y1v) || (tx && !x1v)) continue;
        int iy = ty ? iy1 : m;
        int ix = tx ? ix1 : n;
        const unsigned short* p = ib + ((size_t)iy * W1 + ix) * C2;
        const float* w = wt2k + ((size_t)par * 4 + t) * 64;
#pragma unroll
        for (int g = 0; g < 4; ++g) {
            s16x8 v8 = ld8(p + g * 8);
#pragma unroll
            for (int e = 0; e < 8; ++e) {
                float v = bf2f((unsigned short)v8[e]);
                int ci = g * 8 + e;
                a0 += v * w[2 * ci];
                a1 += v * w[2 * ci + 1];
            }
        }
    }
    int oy = 2 * m + ry, ox = 2 * n + rx;
    size_t base_o = (size_t)b * (H0 * W0) + (size_t)oy * W0 + ox;
    out[base_o] = fmaxf(a0, 0.f) + log1pf(expf(-fabsf(a0)));
    out[(size_t)NB * H0 * W0 + base_o] = fmaxf(a1, 0.f) + log1pf(expf(-fabsf(a1)));
}

extern "C" void kernel_launch(void* const* d_in, const int* in_sizes, int n_in,
                              void* d_out, int out_size, void* d_ws, size_t ws_size,
                              hipStream_t stream) {
    const float* x   = (const float*)d_in[0];
    const float* w1  = (const float*)d_in[1];
    const float* w2  = (const float*)d_in[2];
    const float* wd  = (const float*)d_in[3];
    const float* bd  = (const float*)d_in[4];
    const float* wt1 = (const float*)d_in[5];
    const float* bt1 = (const float*)d_in[6];
    const float* wt2 = (const float*)d_in[7];
    const float* bt2 = (const float*)d_in[8];
    float* out = (float*)d_out;

    char* ws = (char*)d_ws;
    // workspace (bytes):
    unsigned short* s1m    = (unsigned short*)(ws);              //  9,420,800
    unsigned short* mem2bf = (unsigned short*)(ws + 9420800);    //  4,710,400
    unsigned short* h1bf   = (unsigned short*)(ws + 14131200);   //  9,420,800
    unsigned short* h2bf   = (unsigned short*)(ws + 23552000);   // 18,841,600
    unsigned long long* xb = (unsigned long long*)(ws + 42393600); // 2,457,600
    unsigned short* wdb    = (unsigned short*)(ws + 44851200);   //     36,864
    unsigned short* wt1b   = (unsigned short*)(ws + 44888064);   //     65,536
    float* wt2k            = (float*)(ws + 44953600);            //      4,096
    unsigned short* w2b3   = (unsigned short*)(ws + 44957696);   //     27,648

    {
        int n = 64 * 288 + 4 * 32 * 256 + 1024 + 3 * 32 * 144; // 66048
        k_repackb<<<(n + 255) / 256, 256, 0, stream>>>(wd, wt1, wt2, w2, wdb, wt1b, wt2k, w2b3);
    }
    {
        long long nthreads = (long long)T_STEPS * NB * H0 * WPR * 64;
        int blocks = (int)((nthreads + 255) / 256);
        k_pack<<<blocks, 256, 0, stream>>>(x, xb);
    }
    {
        int n = NB * H1 * W1;
        k_snn1<<<(n + 255) / 256, 256, 0, stream>>>(xb, w1, s1m);
    }
    {
        // 73600 sites / 32 per wave / 4 waves per block = 575 blocks exactly
        k_snn2<<<575, 256, 0, stream>>>(s1m, w2b3, mem2bf);
    }
    {
        dim3 g(18, 1, NB);
        k_convd<<<g, 256, 0, stream>>>(mem2bf, wdb, bd, h1bf);
    }
    {
        dim3 g(9, 4, NB);
        k_convt1<<<g, 256, 0, stream>>>(h1bf, wt1b, bt1, h2bf);
    }
    {
        dim3 g(36, 4, NB);
        k_convt2<<<g, 256, 0, stream>>>(h2bf, wt2k, bt2, out);
    }
}

// Round 6
// 200.156 us; speedup vs baseline: 18.2004x; 1.0362x over previous
//
#include <hip/hip_runtime.h>
#include <hip/hip_bf16.h>
#include <cstddef>

// Shapes (fixed):
// x_seq: (T=16, B=32, 1, 100, 368) binary {0,1} fp32
// conv1: w1 (16,1,5,5) s2 p2   -> (32,16,50,184)  [MFMA bf16 3-term split, LIF in acc]
// conv2: w2 (32,16,3,3) s2 p1  -> (32,32,25,92)   [MFMA bf16 3-term split, LIF in acc]
// convd: wd (64,32,3,3) s1 p1  -> (32,64,25,92), relu        [MFMA bf16]
// convT1: wt1 (64,32,4,4) s2 p1 -> (32,32,50,184), relu      [MFMA bf16, parity-split]
// convT2: wt2 (32,2,4,4) s2 p1  -> (32,2,100,368), softplus  [VALU, bf16 reads]

#define T_STEPS 16
#define NB 32
#define H0 100
#define W0 368
#define C1 16
#define H1 50
#define W1 184
#define C2 32
#define H2 25
#define W2 92
#define CD 64
#define WPR 6
#define SITES2 2300   // 25*92
#define SITES1 9200   // 50*184

using f32x16 = __attribute__((ext_vector_type(16))) float;
using f32x4  = __attribute__((ext_vector_type(4))) float;
using s16x8  = __attribute__((ext_vector_type(8))) short;

__device__ inline unsigned short f2bf(float f) {
    union { float f; unsigned int u; } v; v.f = f;
    unsigned int r = v.u + 0x7fffu + ((v.u >> 16) & 1u);  // RNE
    return (unsigned short)(r >> 16);
}
__device__ inline float bf2f(unsigned short u) {
    union { unsigned int u; float f; } v; v.u = ((unsigned int)u) << 16;
    return v.f;
}
__device__ inline unsigned int pk2(float a, float b) {
    return (unsigned int)f2bf(a) | ((unsigned int)f2bf(b) << 16);
}
__device__ inline s16x8 ld8(const void* p) { return *reinterpret_cast<const s16x8*>(p); }

// ---------------- Kernel P: bit-pack binary input ----------------
__global__ __launch_bounds__(256) void k_pack(const float* __restrict__ x,
                                              unsigned long long* __restrict__ xb) {
    long long gid = (long long)blockIdx.x * blockDim.x + threadIdx.x;
    long long widx = gid >> 6;
    int lane = (int)(gid & 63);
    const long long NWORDS = (long long)T_STEPS * NB * H0 * WPR;
    if (widx >= NWORDS) return;
    int wcol = (int)(widx % WPR);
    long long rowid = widx / WPR;
    int y = (int)(rowid % H0);
    long long tb = rowid / H0;
    int col = wcol * 64 + lane;
    float v = 0.f;
    if (col < W0) v = x[(tb * H0 + y) * W0 + col];
    unsigned long long mask = __ballot(v != 0.f);
    if (lane == 0) xb[widx] = mask;
}

// ---------------- Kernel A: conv1+LIF fused MFMA over 16 timesteps ----------------
// wave = 64 sites x 16 co (4 MFMA groups of 16 sites); m1 state in accumulators.
// Each lane builds its own site's 25-bit tap mask; shfl distributes per group.
// Weights: 3-term bf16 split (exact to < fp32 ulp), hoisted in VGPRs.
__global__ __launch_bounds__(256) void k_snn1(const unsigned long long* __restrict__ xb,
                                              const unsigned short* __restrict__ w1b3,
                                              unsigned short* __restrict__ s1m) {
    __shared__ uint4 lut[256];
    {
        int m = (int)threadIdx.x;  // exactly 256 threads
        unsigned int wv[4];
#pragma unroll
        for (int h = 0; h < 4; ++h) {
            unsigned int lo = (m >> (2 * h)) & 1u, hb = (m >> (2 * h + 1)) & 1u;
            wv[h] = (lo ? 0x3F80u : 0u) | (hb ? 0x3F800000u : 0u);
        }
        lut[m] = make_uint4(wv[0], wv[1], wv[2], wv[3]);
    }
    __syncthreads();

    int wave = threadIdx.x >> 6;
    int lane = threadIdx.x & 63;
    int col = lane & 15;   // D col (site within group) / A row (co)
    int hi  = lane >> 4;   // k-slice index; D row group
    const int NPOS = NB * H1 * W1;  // 294400 = 1150*256
    int base = (blockIdx.x * 4 + wave) * 64;

    // own-site coords (for tap-mask build)
    int site = base + lane;
    int x1 = site % W1;
    int tq = site / W1;
    int y1 = tq % H1;
    int b  = tq / H1;
    const int iy0 = 2 * y1 - 2;
    const int ix0 = 2 * x1 - 2;
    const int wi = ix0 >> 6;
    const int sh = ix0 & 63;

    // hoisted A fragments: w1b3[p][co16][k32], lane elem j: co=col, k=hi*8+j
    s16x8 af0 = ld8((const char*)w1b3 + (size_t)((0 * 16 + col) * 32 + hi * 8) * 2);
    s16x8 af1 = ld8((const char*)w1b3 + (size_t)((1 * 16 + col) * 32 + hi * 8) * 2);
    s16x8 af2 = ld8((const char*)w1b3 + (size_t)((2 * 16 + col) * 32 + hi * 8) * 2);

    f32x4 acc0 = {}, acc1 = {}, acc2 = {}, acc3 = {};

    for (int t = 0; t < T_STEPS; ++t) {
        // decay
#pragma unroll
        for (int e = 0; e < 4; ++e) {
            acc0[e] *= 0.5f; acc1[e] *= 0.5f; acc2[e] *= 0.5f; acc3[e] *= 0.5f;
        }
        // own-site 25-bit tap mask
        const unsigned long long* xp = xb + ((size_t)(t * NB + b) * H0) * WPR;
        unsigned int bits25 = 0;
#pragma unroll
        for (int ky = 0; ky < 5; ++ky) {
            int iy = iy0 + ky;
            if (iy < 0 || iy >= H0) continue;
            const unsigned long long* row = xp + (size_t)iy * WPR;
            unsigned long long a = (wi >= 0) ? row[wi] : 0ull;
            unsigned long long bw = (wi + 1 < WPR) ? row[wi + 1] : 0ull;
            unsigned long long chunk = a >> sh;
            if (sh) chunk |= (bw << (64 - sh));
            bits25 |= ((unsigned int)chunk & 31u) << (5 * ky);
        }
        // 4 groups of 16 sites
#pragma unroll
        for (int g = 0; g < 4; ++g) {
            unsigned int sb = __shfl(bits25, g * 16 + col, 64);
            unsigned int byte = (sb >> (hi * 8)) & 0xFFu;
            s16x8 bf = *reinterpret_cast<const s16x8*>(&lut[byte]);
            f32x4& ac = (g == 0) ? acc0 : (g == 1) ? acc1 : (g == 2) ? acc2 : acc3;
            ac = __builtin_amdgcn_mfma_f32_16x16x32_bf16(af0, bf, ac, 0, 0, 0);
            ac = __builtin_amdgcn_mfma_f32_16x16x32_bf16(af1, bf, ac, 0, 0, 0);
            ac = __builtin_amdgcn_mfma_f32_16x16x32_bf16(af2, bf, ac, 0, 0, 0);
        }
        // threshold + reset + spike-mask output
#pragma unroll
        for (int g = 0; g < 4; ++g) {
            f32x4& ac = (g == 0) ? acc0 : (g == 1) ? acc1 : (g == 2) ? acc2 : acc3;
            unsigned int nib = 0;
#pragma unroll
            for (int e = 0; e < 4; ++e) {
                float v = ac[e];
                bool s = (v >= 1.0f);
                if (s) nib |= (1u << e);
                ac[e] = s ? 0.f : v;
            }
            unsigned int mk = nib << (hi * 4);   // co = hi*4 + e
            mk |= __shfl_xor(mk, 16, 64);
            mk |= __shfl_xor(mk, 32, 64);
            if (lane < 16)
                s1m[(size_t)t * NPOS + base + g * 16 + lane] = (unsigned short)mk;
        }
    }
}

// ---------------- Kernel B: conv2+LIF fused MFMA over 16 timesteps ----------------
__global__ __launch_bounds__(256) void k_snn2(const unsigned short* __restrict__ s1m,
                                              const unsigned short* __restrict__ w2b3,
                                              unsigned short* __restrict__ mem2bf) {
    __shared__ uint4 lut[256];
    {
        int m = (int)threadIdx.x;
        unsigned int wv[4];
#pragma unroll
        for (int h = 0; h < 4; ++h) {
            unsigned int lo = (m >> (2 * h)) & 1u, hb = (m >> (2 * h + 1)) & 1u;
            wv[h] = (lo ? 0x3F80u : 0u) | (hb ? 0x3F800000u : 0u);
        }
        lut[m] = make_uint4(wv[0], wv[1], wv[2], wv[3]);
    }
    __syncthreads();

    int wave = threadIdx.x >> 6;
    int lane = threadIdx.x & 63;
    int col = lane & 31, hi = lane >> 5;
    int gsite = (blockIdx.x * 4 + wave) * 32 + col;
    int b = gsite / SITES2;
    int rest = gsite % SITES2;
    int y2 = rest / W2, x2 = rest % W2;

    int toff[9]; bool tval[9];
#pragma unroll
    for (int ky = 0; ky < 3; ++ky)
#pragma unroll
        for (int kx = 0; kx < 3; ++kx) {
            int iy = 2 * y2 + ky - 1, ix = 2 * x2 + kx - 1;
            tval[ky * 3 + kx] = iy >= 0 && iy < H1 && ix >= 0 && ix < W1;
            toff[ky * 3 + kx] = iy * W1 + ix;
        }

    const char* ab = (const char*)w2b3;
    s16x8 a0[9], a1[9], a2[9];
#pragma unroll
    for (int s = 0; s < 9; ++s) {
        int ko = (s * 16 + hi * 8) * 2;
        a0[s] = ld8(ab + (col * 144) * 2 + ko);
        a1[s] = ld8(ab + ((32 + col) * 144) * 2 + ko);
        a2[s] = ld8(ab + ((64 + col) * 144) * 2 + ko);
    }

    f32x16 acc = {};
    int hsh = hi * 8;

    for (int t = 0; t < T_STEPS; ++t) {
        const unsigned short* spk = s1m + (size_t)t * (NB * H1 * W1) + (size_t)b * (H1 * W1);
        unsigned int msk[9];
#pragma unroll
        for (int i = 0; i < 9; ++i)
            msk[i] = tval[i] ? (unsigned int)spk[toff[i]] : 0u;

#pragma unroll
        for (int e = 0; e < 16; ++e) acc[e] *= 0.5f;

#pragma unroll
        for (int s = 0; s < 9; ++s) {
            unsigned int byte = (msk[s] >> hsh) & 0xFFu;
            s16x8 bf = *reinterpret_cast<const s16x8*>(&lut[byte]);
            acc = __builtin_amdgcn_mfma_f32_32x32x16_bf16(a0[s], bf, acc, 0, 0, 0);
            acc = __builtin_amdgcn_mfma_f32_32x32x16_bf16(a1[s], bf, acc, 0, 0, 0);
            acc = __builtin_amdgcn_mfma_f32_32x32x16_bf16(a2[s], bf, acc, 0, 0, 0);
        }
#pragma unroll
        for (int e = 0; e < 16; ++e) {
            float v = acc[e];
            acc[e] = (v >= 1.0f) ? 0.f : v;
        }
    }

    char* obase = (char*)(mem2bf + (size_t)gsite * C2);
#pragma unroll
    for (int q = 0; q < 4; ++q) {
        int co = 8 * q + 4 * hi;
        uint2 u;
        u.x = pk2(acc[4 * q + 0], acc[4 * q + 1]);
        u.y = pk2(acc[4 * q + 2], acc[4 * q + 3]);
        *(uint2*)(obase + co * 2) = u;
    }
}

// ---------------- Kernel R: repack weights ----------------
// wdb [co64][k288] bf16 ; wt1b[par4][co32][k256] bf16 ; wt2k[par4][tap4][ci32][co2] fp32
// w2b3[term3][co32][k144] bf16 ; w1b3[term3][co16][k32] bf16
__global__ __launch_bounds__(256) void k_repackb(const float* __restrict__ wd,
                                                 const float* __restrict__ wt1,
                                                 const float* __restrict__ wt2,
                                                 const float* __restrict__ w2,
                                                 const float* __restrict__ w1,
                                                 unsigned short* __restrict__ wdb,
                                                 unsigned short* __restrict__ wt1b,
                                                 float* __restrict__ wt2k,
                                                 unsigned short* __restrict__ w2b3,
                                                 unsigned short* __restrict__ w1b3) {
    int gid = blockIdx.x * blockDim.x + threadIdx.x;
    if (gid < 64 * 288) {
        int co = gid / 288, k = gid % 288;
        int tap = k >> 5, ci = k & 31;
        wdb[gid] = f2bf(wd[((size_t)co * C2 + ci) * 9 + tap]);
    } else if (gid < 64 * 288 + 4 * 32 * 256) {
        int j = gid - 64 * 288;
        int par = j >> 13, co = (j >> 8) & 31, k = j & 255;
        int tap = k >> 6, ci = k & 63;
        int ty = tap >> 1, tx = tap & 1;
        int ry = par >> 1, rx = par & 1;
        int ky = ry ? (ty ? 0 : 2) : (ty ? 3 : 1);
        int kx = rx ? (tx ? 0 : 2) : (tx ? 3 : 1);
        wt1b[j] = f2bf(wt1[(((size_t)ci * 32 + co) * 4 + ky) * 4 + kx]);
    } else if (gid < 64 * 288 + 4 * 32 * 256 + 1024) {
        int j = gid - (64 * 288 + 4 * 32 * 256);
        int par = j >> 8, tap = (j >> 6) & 3, ci = (j >> 1) & 31, co = j & 1;
        int ty = tap >> 1, tx = tap & 1;
        int ry = par >> 1, rx = par & 1;
        int ky = ry ? (ty ? 0 : 2) : (ty ? 3 : 1);
        int kx = rx ? (tx ? 0 : 2) : (tx ? 3 : 1);
        wt2k[j] = wt2[(((size_t)ci * 2 + co) * 4 + ky) * 4 + kx];
    } else if (gid < 64 * 288 + 4 * 32 * 256 + 1024 + 3 * 32 * 144) {
        int j = gid - (64 * 288 + 4 * 32 * 256 + 1024);
        int p = j / 4608, rem = j % 4608;
        int co = rem / 144, k = rem % 144;
        int tap = k / 16, ci = k % 16;
        float w = w2[((size_t)co * C1 + ci) * 9 + tap];
        unsigned short b0 = f2bf(w);
        float r1 = w - bf2f(b0);
        unsigned short b1 = f2bf(r1);
        float r2 = r1 - bf2f(b1);
        unsigned short b2 = f2bf(r2);
        w2b3[j] = (p == 0) ? b0 : (p == 1) ? b1 : b2;
    } else if (gid < 64 * 288 + 4 * 32 * 256 + 1024 + 3 * 32 * 144 + 3 * 16 * 32) {
        int j = gid - (64 * 288 + 4 * 32 * 256 + 1024 + 3 * 32 * 144);
        int p = j / 512, rem = j % 512;
        int co = rem / 32, k = rem % 32;
        float w = (k < 25) ? w1[co * 25 + k] : 0.f;
        unsigned short b0 = f2bf(w);
        float r1 = w - bf2f(b0);
        unsigned short b1 = f2bf(r1);
        float r2 = r1 - bf2f(b1);
        unsigned short b2 = f2bf(r2);
        w1b3[j] = (p == 0) ? b0 : (p == 1) ? b1 : b2;
    }
}

// ---------------- Kernel C: convd via MFMA ----------------
__global__ __launch_bounds__(256) void k_convd(const unsigned short* __restrict__ mem2bf,
                                               const unsigned short* __restrict__ wdb,
                                               const float* __restrict__ bd,
                                               unsigned short* __restrict__ h1bf) {
    int wave = threadIdx.x >> 6;
    int lane = threadIdx.x & 63;
    int col = lane & 31, hi = lane >> 5;
    int b = blockIdx.z;
    int n0 = (blockIdx.x * 4 + wave) * 32;
    int site = n0 + col;
    bool sval = site < SITES2;
    int sc = sval ? site : 0;
    int yy = sc / W2, xx = sc % W2;

    const char* ibase = (const char*)(mem2bf + (size_t)b * SITES2 * C2);
    int toff[9];
    bool tval[9];
#pragma unroll
    for (int ky = 0; ky < 3; ++ky)
#pragma unroll
        for (int kx = 0; kx < 3; ++kx) {
            int iy = yy + ky - 1, ix = xx + kx - 1;
            bool v = sval && iy >= 0 && iy < H2 && ix >= 0 && ix < W2;
            tval[ky * 3 + kx] = v;
            toff[ky * 3 + kx] = (iy * W2 + ix) * (C2 * 2);
        }

    const char* abase = (const char*)wdb;
    f32x16 acc0 = {}, acc1 = {};
    const s16x8 zero = {0, 0, 0, 0, 0, 0, 0, 0};
#pragma unroll
    for (int s = 0; s < 18; ++s) {
        int tap = s >> 1;
        int boff = (s & 1) * 32 + hi * 16;
        s16x8 bf = tval[tap] ? ld8(ibase + toff[tap] + boff) : zero;
        s16x8 a0 = ld8(abase + col * 576 + s * 32 + hi * 16);
        s16x8 a1 = ld8(abase + (col + 32) * 576 + s * 32 + hi * 16);
        acc0 = __builtin_amdgcn_mfma_f32_32x32x16_bf16(a0, bf, acc0, 0, 0, 0);
        acc1 = __builtin_amdgcn_mfma_f32_32x32x16_bf16(a1, bf, acc1, 0, 0, 0);
    }
    if (!sval) return;
    char* obase = (char*)(h1bf + ((size_t)b * SITES2 + site) * CD);
#pragma unroll
    for (int t = 0; t < 2; ++t) {
        const f32x16& ac = t ? acc1 : acc0;
#pragma unroll
        for (int q = 0; q < 4; ++q) {
            int co = t * 32 + 8 * q + 4 * hi;
            float v0 = fmaxf(ac[4 * q + 0] + bd[co + 0], 0.f);
            float v1 = fmaxf(ac[4 * q + 1] + bd[co + 1], 0.f);
            float v2 = fmaxf(ac[4 * q + 2] + bd[co + 2], 0.f);
            float v3 = fmaxf(ac[4 * q + 3] + bd[co + 3], 0.f);
            uint2 u; u.x = pk2(v0, v1); u.y = pk2(v2, v3);
            *(uint2*)(obase + co * 2) = u;
        }
    }
}

// ---------------- Kernel D: convt1 via MFMA, parity-split ----------------
__global__ __launch_bounds__(256) void k_convt1(const unsigned short* __restrict__ h1bf,
                                                const unsigned short* __restrict__ wt1b,
                                                const float* __restrict__ bt1,
                                                unsigned short* __restrict__ h2bf) {
    int wave = threadIdx.x >> 6;
    int lane = threadIdx.x & 63;
    int col = lane & 31, hi = lane >> 5;
    int par = blockIdx.y;
    int ry = par >> 1, rx = par & 1;
    int b = blockIdx.z;
    int n0 = (blockIdx.x * 4 + wave) * 64;

    const char* ibase = (const char*)(h1bf + (size_t)b * SITES2 * CD);
    int toff[2][4];
    bool tval[2][4];
    int mm[2], nn[2];
    bool sv[2];
#pragma unroll
    for (int j = 0; j < 2; ++j) {
        int site = n0 + j * 32 + col;
        sv[j] = site < SITES2;
        int sc = sv[j] ? site : 0;
        int m = sc / W2, n = sc % W2;
        mm[j] = m; nn[j] = n;
        int iy1 = m + (ry ? 1 : -1);
        int ix1 = n + (rx ? 1 : -1);
        bool y1v = iy1 >= 0 && iy1 < H2;
        bool x1v = ix1 >= 0 && ix1 < W2;
#pragma unroll
        for (int t = 0; t < 4; ++t) {
            int ty = t >> 1, tx = t & 1;
            int iy = ty ? iy1 : m;
            int ix = tx ? ix1 : n;
            tval[j][t] = sv[j] && (ty ? y1v : true) && (tx ? x1v : true);
            toff[j][t] = (iy * W2 + ix) * (CD * 2);
        }
    }

    const char* abase = (const char*)(wt1b + (size_t)par * 32 * 256);
    f32x16 acc0 = {}, acc1 = {};
    const s16x8 zero = {0, 0, 0, 0, 0, 0, 0, 0};
#pragma unroll
    for (int s = 0; s < 16; ++s) {
        int tap = s >> 2;
        int boff = (s & 3) * 32 + hi * 16;
        s16x8 b0 = tval[0][tap] ? ld8(ibase + toff[0][tap] + boff) : zero;
        s16x8 b1 = tval[1][tap] ? ld8(ibase + toff[1][tap] + boff) : zero;
        s16x8 a = ld8(abase + col * 512 + s * 32 + hi * 16);
        acc0 = __builtin_amdgcn_mfma_f32_32x32x16_bf16(a, b0, acc0, 0, 0, 0);
        acc1 = __builtin_amdgcn_mfma_f32_32x32x16_bf16(a, b1, acc1, 0, 0, 0);
    }
#pragma unroll
    for (int j = 0; j < 2; ++j) {
        if (!sv[j]) continue;
        const f32x16& ac = j ? acc1 : acc0;
        int oy = 2 * mm[j] + ry, ox = 2 * nn[j] + rx;
        char* obase = (char*)(h2bf + ((size_t)b * SITES1 + (size_t)oy * W1 + ox) * C2);
#pragma unroll
        for (int q = 0; q < 4; ++q) {
            int co = 8 * q + 4 * hi;
            float v0 = fmaxf(ac[4 * q + 0] + bt1[co + 0], 0.f);
            float v1 = fmaxf(ac[4 * q + 1] + bt1[co + 1], 0.f);
            float v2 = fmaxf(ac[4 * q + 2] + bt1[co + 2], 0.f);
            float v3 = fmaxf(ac[4 * q + 3] + bt1[co + 3], 0.f);
            uint2 u; u.x = pk2(v0, v1); u.y = pk2(v2, v3);
            *(uint2*)(obase + co * 2) = u;
        }
    }
}

// ---------------- Kernel E: convt2 VALU, bf16 channel-last input ----------------
__global__ __launch_bounds__(256) void k_convt2(const unsigned short* __restrict__ h2bf,
                                                const float* __restrict__ wt2k,
                                                const float* __restrict__ bt2,
                                                float* __restrict__ out) {
    int i = blockIdx.x * blockDim.x + threadIdx.x;
    if (i >= SITES1) return;
    int par = blockIdx.y;
    int ry = par >> 1, rx = par & 1;
    int b = blockIdx.z;
    int m = i / W1, n = i % W1;
    int iy1 = m + (ry ? 1 : -1);
    int ix1 = n + (rx ? 1 : -1);
    bool y1v = iy1 >= 0 && iy1 < H1;
    bool x1v = ix1 >= 0 && ix1 < W1;

    float a0 = bt2[0], a1 = bt2[1];
    const unsigned short* ib = h2bf + (size_t)b * SITES1 * C2;
#pragma unroll
    for (int t = 0; t < 4; ++t) {
        int ty = t >> 1, tx = t & 1;
        if ((ty && !y1v) || (tx && !x1v)) continue;
        int iy = ty ? iy1 : m;
        int ix = tx ? ix1 : n;
        const unsigned short* p = ib + ((size_t)iy * W1 + ix) * C2;
        const float* w = wt2k + ((size_t)par * 4 + t) * 64;
#pragma unroll
        for (int g = 0; g < 4; ++g) {
            s16x8 v8 = ld8(p + g * 8);
#pragma unroll
            for (int e = 0; e < 8; ++e) {
                float v = bf2f((unsigned short)v8[e]);
                int ci = g * 8 + e;
                a0 += v * w[2 * ci];
                a1 += v * w[2 * ci + 1];
            }
        }
    }
    int oy = 2 * m + ry, ox = 2 * n + rx;
    size_t base_o = (size_t)b * (H0 * W0) + (size_t)oy * W0 + ox;
    out[base_o] = fmaxf(a0, 0.f) + log1pf(expf(-fabsf(a0)));
    out[(size_t)NB * H0 * W0 + base_o] = fmaxf(a1, 0.f) + log1pf(expf(-fabsf(a1)));
}

extern "C" void kernel_launch(void* const* d_in, const int* in_sizes, int n_in,
                              void* d_out, int out_size, void* d_ws, size_t ws_size,
                              hipStream_t stream) {
    const float* x   = (const float*)d_in[0];
    const float* w1  = (const float*)d_in[1];
    const float* w2  = (const float*)d_in[2];
    const float* wd  = (const float*)d_in[3];
    const float* bd  = (const float*)d_in[4];
    const float* wt1 = (const float*)d_in[5];
    const float* bt1 = (const float*)d_in[6];
    const float* wt2 = (const float*)d_in[7];
    const float* bt2 = (const float*)d_in[8];
    float* out = (float*)d_out;

    char* ws = (char*)d_ws;
    // workspace (bytes):
    unsigned short* s1m    = (unsigned short*)(ws);              //  9,420,800
    unsigned short* mem2bf = (unsigned short*)(ws + 9420800);    //  4,710,400
    unsigned short* h1bf   = (unsigned short*)(ws + 14131200);   //  9,420,800
    unsigned short* h2bf   = (unsigned short*)(ws + 23552000);   // 18,841,600
    unsigned long long* xb = (unsigned long long*)(ws + 42393600); // 2,457,600
    unsigned short* wdb    = (unsigned short*)(ws + 44851200);   //     36,864
    unsigned short* wt1b   = (unsigned short*)(ws + 44888064);   //     65,536
    float* wt2k            = (float*)(ws + 44953600);            //      4,096
    unsigned short* w2b3   = (unsigned short*)(ws + 44957696);   //     27,648
    unsigned short* w1b3   = (unsigned short*)(ws + 44985344);   //      3,072

    {
        int n = 64 * 288 + 4 * 32 * 256 + 1024 + 3 * 32 * 144 + 3 * 16 * 32; // 67584
        k_repackb<<<(n + 255) / 256, 256, 0, stream>>>(wd, wt1, wt2, w2, w1,
                                                       wdb, wt1b, wt2k, w2b3, w1b3);
    }
    {
        long long nthreads = (long long)T_STEPS * NB * H0 * WPR * 64;
        int blocks = (int)((nthreads + 255) / 256);
        k_pack<<<blocks, 256, 0, stream>>>(x, xb);
    }
    {
        // 294400 sites / 64 per wave / 4 waves per block = 1150 blocks exactly
        k_snn1<<<1150, 256, 0, stream>>>(xb, w1b3, s1m);
    }
    {
        // 73600 sites / 32 per wave / 4 waves per block = 575 blocks exactly
        k_snn2<<<575, 256, 0, stream>>>(s1m, w2b3, mem2bf);
    }
    {
        dim3 g(18, 1, NB);
        k_convd<<<g, 256, 0, stream>>>(mem2bf, wdb, bd, h1bf);
    }
    {
        dim3 g(9, 4, NB);
        k_convt1<<<g, 256, 0, stream>>>(h1bf, wt1b, bt1, h2bf);
    }
    {
        dim3 g(36, 4, NB);
        k_convt2<<<g, 256, 0, stream>>>(h2bf, wt2k, bt2, out);
    }
}